// Round 1
// baseline (5998.075 us; speedup 1.0000x reference)
//
#include <hip/hip_runtime.h>
#include <hip/hip_bf16.h>

#define B_ 64
#define N_ 1024
#define E_ 512
#define D_ 1024
#define M_ 16
#define T_ 12
#define P_ 2048
#define HS_ 2048
#define HN_ 64
#define C_ 4
#define NH_ 8
#define DH_ 64

__device__ __forceinline__ float bf2f(unsigned int u) {
    union { unsigned int i; float f; } c; c.i = (u & 0xffffu) << 16; return c.f;
}
__device__ __forceinline__ unsigned short f2bf(float f) {
    union { float f; unsigned int i; } c; c.f = f;
    unsigned int x = c.i;
    unsigned int r = x + 0x7fffu + ((x >> 16) & 1u);
    return (unsigned short)(r >> 16);
}

// ---------------- init state ----------------
__global__ void init_kernel(float* s_a, float* a_a, float* b_a, float* a_o, float* b_o, float* z) {
    int i = blockIdx.x * 256 + threadIdx.x;
    if (i < B_ * P_) {
        s_a[i] = 0.f; a_a[i] = 0.f; b_a[i] = 1.f; a_o[i] = 0.f; b_o[i] = 1.f;
    }
    if (i < B_ * D_) z[i] = 0.f;
}

// ---------------- KV projection: out[m, j] = kv[m,:] . W[512+j,:] + b[512+j], bf16 store ----------------
__global__ __launch_bounds__(256) void kvproj_kernel(const float* __restrict__ kv,
                                                     const float* __restrict__ Wfull,
                                                     const float* __restrict__ bfull,
                                                     __hip_bfloat16* __restrict__ out) {
    __shared__ float As[16][68];
    __shared__ float Bs[16][68];
    const float* W = Wfull + (size_t)E_ * E_;  // rows 512..1535 of in_proj_w (Wk;Wv)
    const float* bias = bfull + E_;
    int m0 = blockIdx.y * 64;
    int j0 = blockIdx.x * 64;
    int tid = threadIdx.x;
    int tx = tid & 15, ty = tid >> 4;
    float acc[4][4] = {};
    for (int k0 = 0; k0 < E_; k0 += 16) {
#pragma unroll
        for (int i = 0; i < 4; i++) {
            int r = ty + i * 16;
            As[tx][r] = kv[(size_t)(m0 + r) * E_ + k0 + tx];
            Bs[tx][r] = W[(size_t)(j0 + r) * E_ + k0 + tx];
        }
        __syncthreads();
#pragma unroll
        for (int kk = 0; kk < 16; kk++) {
            float4 a = *(const float4*)&As[kk][ty * 4];
            float4 b = *(const float4*)&Bs[kk][tx * 4];
            acc[0][0] += a.x * b.x; acc[0][1] += a.x * b.y; acc[0][2] += a.x * b.z; acc[0][3] += a.x * b.w;
            acc[1][0] += a.y * b.x; acc[1][1] += a.y * b.y; acc[1][2] += a.y * b.z; acc[1][3] += a.y * b.w;
            acc[2][0] += a.z * b.x; acc[2][1] += a.z * b.y; acc[2][2] += a.z * b.z; acc[2][3] += a.z * b.w;
            acc[3][0] += a.w * b.x; acc[3][1] += a.w * b.y; acc[3][2] += a.w * b.z; acc[3][3] += a.w * b.w;
        }
        __syncthreads();
    }
    int j = j0 + tx * 4;
    float b0 = bias[j + 0], b1 = bias[j + 1], b2 = bias[j + 2], b3 = bias[j + 3];
#pragma unroll
    for (int i = 0; i < 4; i++) {
        int m = m0 + ty * 4 + i;
        ushort4 pk;
        pk.x = f2bf(acc[i][0] + b0);
        pk.y = f2bf(acc[i][1] + b1);
        pk.z = f2bf(acc[i][2] + b2);
        pk.w = f2bf(acc[i][3] + b3);
        *reinterpret_cast<ushort4*>(out + (size_t)m * 1024 + j) = pk;
    }
}

// ---------------- wave reduce helpers ----------------
__device__ __forceinline__ float wave_max64(float v) {
#pragma unroll
    for (int off = 32; off >= 1; off >>= 1) v = fmaxf(v, __shfl_xor(v, off, 64));
    return v;
}
__device__ __forceinline__ float wave_sum64(float v) {
#pragma unroll
    for (int off = 32; off >= 1; off >>= 1) v += __shfl_xor(v, off, 64);
    return v;
}

// ---------------- query: q = s_a @ q_w.T + q_b ; qh = q @ Wq.T + bq ----------------
__global__ __launch_bounds__(256) void query_kernel(const float* __restrict__ s_a,
                                                    const float* __restrict__ q_w,
                                                    const float* __restrict__ q_b,
                                                    const float* __restrict__ in_proj_w,
                                                    const float* __restrict__ in_proj_b,
                                                    float* __restrict__ qh) {
    int b = blockIdx.x;
    int tid = threadIdx.x;
    __shared__ float sa[P_];
    __shared__ float q[E_];
    for (int p = tid; p < P_; p += 256) sa[p] = s_a[(size_t)b * P_ + p];
    __syncthreads();
    for (int e = tid; e < E_; e += 256) {
        const float* wr = q_w + (size_t)e * P_;
        float acc = 0.f;
        for (int p = 0; p < P_; p += 4) {
            float4 wv = *(const float4*)(wr + p);
            acc += wv.x * sa[p] + wv.y * sa[p + 1] + wv.z * sa[p + 2] + wv.w * sa[p + 3];
        }
        q[e] = acc + q_b[e];
    }
    __syncthreads();
    for (int e = tid; e < E_; e += 256) {
        const float* wr = in_proj_w + (size_t)e * E_;  // Wq row e
        float acc = 0.f;
        for (int k = 0; k < E_; k += 4) {
            float4 wv = *(const float4*)(wr + k);
            acc += wv.x * q[k] + wv.y * q[k + 1] + wv.z * q[k + 2] + wv.w * q[k + 3];
        }
        qh[(size_t)b * E_ + e] = acc + in_proj_b[e];
    }
}

// ---------------- attention for one (b,h): scores->softmax->o ----------------
__global__ __launch_bounds__(256) void attn_kernel(const __hip_bfloat16* __restrict__ kvbuf,
                                                   const float* __restrict__ qh,
                                                   float* __restrict__ o) {
    int bh = blockIdx.x;
    int b = bh >> 3, h = bh & 7;
    __shared__ float sc[N_];
    __shared__ float qv[DH_];
    __shared__ float red[8];
    __shared__ float opart[4][DH_];
    int tid = threadIdx.x;
    int w = tid >> 6, lane = tid & 63;
    if (tid < DH_) qv[tid] = qh[(size_t)b * E_ + h * DH_ + tid];
    __syncthreads();
    const __hip_bfloat16* kb = kvbuf + (size_t)b * N_ * 1024 + h * DH_;
    float myv[4];
#pragma unroll
    for (int i = 0; i < 4; i++) {
        int n = tid + i * 256;
        const __hip_bfloat16* kr = kb + (size_t)n * 1024;
        float s = 0.f;
#pragma unroll
        for (int d = 0; d < DH_; d += 8) {
            uint4 pk = *(const uint4*)(kr + d);
            s += bf2f(pk.x) * qv[d + 0] + bf2f(pk.x >> 16) * qv[d + 1]
               + bf2f(pk.y) * qv[d + 2] + bf2f(pk.y >> 16) * qv[d + 3]
               + bf2f(pk.z) * qv[d + 4] + bf2f(pk.z >> 16) * qv[d + 5]
               + bf2f(pk.w) * qv[d + 6] + bf2f(pk.w >> 16) * qv[d + 7];
        }
        myv[i] = s * 0.125f;  // 1/sqrt(64)
    }
    float m = fmaxf(fmaxf(myv[0], myv[1]), fmaxf(myv[2], myv[3]));
    m = wave_max64(m);
    if (lane == 0) red[w] = m;
    __syncthreads();
    m = fmaxf(fmaxf(red[0], red[1]), fmaxf(red[2], red[3]));
    float s = 0.f;
#pragma unroll
    for (int i = 0; i < 4; i++) {
        float e = expf(myv[i] - m);
        sc[tid + i * 256] = e;
        s += e;
    }
    s = wave_sum64(s);
    if (lane == 0) red[4 + w] = s;
    __syncthreads();
    float inv = 1.0f / (red[4] + red[5] + red[6] + red[7]);
    const unsigned short* vb = (const unsigned short*)(kvbuf + (size_t)b * N_ * 1024 + E_ + h * DH_);
    float a0 = 0.f, a1 = 0.f;
    int n0 = w * 256;
    for (int i = 0; i < 256; i += 2) {
        a0 += sc[n0 + i]     * bf2f(vb[(size_t)(n0 + i)     * 1024 + lane]);
        a1 += sc[n0 + i + 1] * bf2f(vb[(size_t)(n0 + i + 1) * 1024 + lane]);
    }
    opart[w][lane] = a0 + a1;
    __syncthreads();
    if (tid < DH_) {
        float r = (opart[0][tid] + opart[1][tid] + opart[2][tid] + opart[3][tid]) * inv;
        o[(size_t)b * E_ + h * DH_ + tid] = r;
    }
}

// ---------------- out_proj + LN(o) + LN(z): fill u=[zn, o_ln], fused[., 1024:]=o_ln ----------------
__global__ __launch_bounds__(256) void oproj_ln_kernel(const float* __restrict__ o_attn,
                                                       const float* __restrict__ Wout,
                                                       const float* __restrict__ bout,
                                                       const float* __restrict__ og,
                                                       const float* __restrict__ obv,
                                                       const float* __restrict__ z,
                                                       const float* __restrict__ zg,
                                                       const float* __restrict__ zbv,
                                                       float* __restrict__ u,
                                                       float* __restrict__ fused) {
    int b = blockIdx.x, tid = threadIdx.x;
    __shared__ float ov[E_];
    __shared__ float red[16];
    for (int e = tid; e < E_; e += 256) ov[e] = o_attn[(size_t)b * E_ + e];
    __syncthreads();
    float v[2];
#pragma unroll
    for (int i = 0; i < 2; i++) {
        int e = tid + i * 256;
        const float* wr = Wout + (size_t)e * E_;
        float acc = 0.f;
        for (int k = 0; k < E_; k += 4) {
            float4 wv = *(const float4*)(wr + k);
            acc += wv.x * ov[k] + wv.y * ov[k + 1] + wv.z * ov[k + 2] + wv.w * ov[k + 3];
        }
        v[i] = acc + bout[e];
    }
    int w = tid >> 6, lane = tid & 63;
    float s1 = v[0] + v[1];
    float s2 = v[0] * v[0] + v[1] * v[1];
#pragma unroll
    for (int off = 32; off >= 1; off >>= 1) { s1 += __shfl_xor(s1, off, 64); s2 += __shfl_xor(s2, off, 64); }
    if (lane == 0) { red[w] = s1; red[4 + w] = s2; }
    __syncthreads();
    s1 = red[0] + red[1] + red[2] + red[3];
    s2 = red[4] + red[5] + red[6] + red[7];
    float mean = s1 * (1.0f / 512.0f);
    float var = s2 * (1.0f / 512.0f) - mean * mean;
    float rstd = 1.0f / sqrtf(var + 1e-5f);
#pragma unroll
    for (int i = 0; i < 2; i++) {
        int e = tid + i * 256;
        float val = (v[i] - mean) * rstd * og[e] + obv[e];
        u[(size_t)b * 1536 + D_ + e] = val;
        fused[(size_t)b * 1536 + D_ + e] = val;
    }
    // LN(z) over D=1024
    float zl[4];
    float t1 = 0.f, t2 = 0.f;
#pragma unroll
    for (int i = 0; i < 4; i++) {
        int d = tid + i * 256;
        zl[i] = z[(size_t)b * D_ + d];
        t1 += zl[i]; t2 += zl[i] * zl[i];
    }
#pragma unroll
    for (int off = 32; off >= 1; off >>= 1) { t1 += __shfl_xor(t1, off, 64); t2 += __shfl_xor(t2, off, 64); }
    __syncthreads();
    if (lane == 0) { red[8 + w] = t1; red[12 + w] = t2; }
    __syncthreads();
    t1 = red[8] + red[9] + red[10] + red[11];
    t2 = red[12] + red[13] + red[14] + red[15];
    float zmean = t1 * (1.0f / 1024.0f);
    float zvar = t2 * (1.0f / 1024.0f) - zmean * zmean;
    float zr = 1.0f / sqrtf(zvar + 1e-5f);
#pragma unroll
    for (int i = 0; i < 4; i++) {
        int d = tid + i * 256;
        u[(size_t)b * 1536 + d] = (zl[i] - zmean) * zr * zg[d] + zbv[d];
    }
}

// ---------------- gate + cand + z_bar: fused[., 0:1024] = (1-g)*zn + g*h ----------------
__global__ __launch_bounds__(256) void gatecand_kernel(const float* __restrict__ u,
                                                       const float* __restrict__ gate_w,
                                                       const float* __restrict__ gate_b,
                                                       const float* __restrict__ cand_w,
                                                       const float* __restrict__ cand_b,
                                                       float* __restrict__ fused) {
    __shared__ float inT[32][68];
    __shared__ float Wg[16][33];
    __shared__ float Wc[16][33];
    int j0 = blockIdx.x * 16;
    int tid = threadIdx.x;
    int tj = tid & 15;
    int tb4 = (tid >> 4) << 2;
    int lb = tid >> 2;
    int lc = (tid & 3) << 2;
    int jr = tid >> 4;
    int c2 = (tid & 15) << 1;
    float accg[4] = {}, accc[4] = {};
    for (int k0 = 0; k0 < 1536; k0 += 32) {
        float4 x0 = *(const float4*)(u + (size_t)lb * 1536 + k0 + lc);
        float4 x1 = *(const float4*)(u + (size_t)lb * 1536 + k0 + lc + 16);
        inT[lc + 0][lb] = x0.x; inT[lc + 1][lb] = x0.y; inT[lc + 2][lb] = x0.z; inT[lc + 3][lb] = x0.w;
        inT[lc + 16][lb] = x1.x; inT[lc + 17][lb] = x1.y; inT[lc + 18][lb] = x1.z; inT[lc + 19][lb] = x1.w;
        float2 wg = *(const float2*)(gate_w + (size_t)(j0 + jr) * 1536 + k0 + c2);
        Wg[jr][c2] = wg.x; Wg[jr][c2 + 1] = wg.y;
        float2 wc = *(const float2*)(cand_w + (size_t)(j0 + jr) * 1536 + k0 + c2);
        Wc[jr][c2] = wc.x; Wc[jr][c2 + 1] = wc.y;
        __syncthreads();
#pragma unroll
        for (int kk = 0; kk < 32; kk++) {
            float4 a = *(const float4*)&inT[kk][tb4];
            float vg = Wg[tj][kk], vc = Wc[tj][kk];
            accg[0] += a.x * vg; accg[1] += a.y * vg; accg[2] += a.z * vg; accg[3] += a.w * vg;
            accc[0] += a.x * vc; accc[1] += a.y * vc; accc[2] += a.z * vc; accc[3] += a.w * vc;
        }
        __syncthreads();
    }
    int j = j0 + tj;
    float gb = gate_b[j], cb = cand_b[j];
#pragma unroll
    for (int i = 0; i < 4; i++) {
        int b = tb4 + i;
        float g = 1.0f / (1.0f + expf(-(accg[i] + gb)));
        float hh = tanhf(accc[i] + cb);
        float zn = u[(size_t)b * 1536 + j];
        fused[(size_t)b * 1536 + j] = (1.0f - g) * zn + g * hh;
    }
}

// ---------------- generic batch-64 linear: out[b,j] = act(in[b,:K] . W[j,:K] + bias[j]) ----------------
template <int ACT>
__global__ __launch_bounds__(256) void blinear_kernel(const float* __restrict__ in, int in_stride, int K,
                                                      const float* __restrict__ W,
                                                      const float* __restrict__ bias,
                                                      float* __restrict__ out, int out_stride) {
    __shared__ float inT[32][68];
    __shared__ float Wt[16][33];
    int j0 = blockIdx.x * 16;
    int tid = threadIdx.x;
    int tj = tid & 15;
    int tb4 = (tid >> 4) << 2;
    int lb = tid >> 2;
    int lc = (tid & 3) << 2;
    int jr = tid >> 4;
    int c2 = (tid & 15) << 1;
    float acc[4] = {};
    for (int k0 = 0; k0 < K; k0 += 32) {
        float4 x0 = *(const float4*)(in + (size_t)lb * in_stride + k0 + lc);
        float4 x1 = *(const float4*)(in + (size_t)lb * in_stride + k0 + lc + 16);
        inT[lc + 0][lb] = x0.x; inT[lc + 1][lb] = x0.y; inT[lc + 2][lb] = x0.z; inT[lc + 3][lb] = x0.w;
        inT[lc + 16][lb] = x1.x; inT[lc + 17][lb] = x1.y; inT[lc + 18][lb] = x1.z; inT[lc + 19][lb] = x1.w;
        float2 wv = *(const float2*)(W + (size_t)(j0 + jr) * K + k0 + c2);
        Wt[jr][c2] = wv.x; Wt[jr][c2 + 1] = wv.y;
        __syncthreads();
#pragma unroll
        for (int kk = 0; kk < 32; kk++) {
            float4 a = *(const float4*)&inT[kk][tb4];
            float wval = Wt[tj][kk];
            acc[0] += a.x * wval; acc[1] += a.y * wval; acc[2] += a.z * wval; acc[3] += a.w * wval;
        }
        __syncthreads();
    }
    int j = j0 + tj;
    float bj = bias[j];
#pragma unroll
    for (int i = 0; i < 4; i++) {
        float val = acc[i] + bj;
        if (ACT == 1) val = 0.5f * val * (1.0f + erff(val * 0.70710678118654752f));
        out[(size_t)(tb4 + i) * out_stride + j] = val;
    }
}

// ---------------- NLM (per-neuron 2-layer GLU MLP over A history) ----------------
template <int NT>
__global__ __launch_bounds__(256) void nlm_kernel(const float* __restrict__ Abuf,
                                                  const float* __restrict__ w1g,
                                                  const float* __restrict__ b1g,
                                                  const float* __restrict__ w2g,
                                                  const float* __restrict__ b2g,
                                                  float* __restrict__ z,
                                                  float* __restrict__ zt) {
    __shared__ float w1s[4][2048];
    __shared__ float b1s[4][128];
    __shared__ float w2s[4][128];
    __shared__ float b2s[4][2];
    int tid = threadIdx.x;
    int w = tid >> 6, lane = tid & 63;
    int d = blockIdx.x * 4 + w;
    for (int i = lane; i < 2048; i += 64) w1s[w][i] = w1g[(size_t)d * 2048 + i];
    for (int i = lane; i < 128; i += 64) {
        b1s[w][i] = b1g[(size_t)d * 128 + i];
        w2s[w][i] = w2g[(size_t)d * 128 + i];
    }
    if (lane < 2) b2s[w][lane] = b2g[d * 2 + lane];
    __syncthreads();
    const int b = lane;
    float av[NT];
#pragma unroll
    for (int s = 0; s < NT; s++) av[s] = Abuf[(size_t)s * (B_ * D_) + (size_t)b * D_ + d];
    constexpr int moff = M_ - NT;  // = 15 - t
    float o0 = b2s[w][0], o1 = b2s[w][1];
    for (int hh = 0; hh < 64; hh++) {
        float a = b1s[w][hh], bb = b1s[w][hh + 64];
#pragma unroll
        for (int s = 0; s < NT; s++) {
            float x = av[s];
            a += x * w1s[w][(s + moff) * 128 + hh];
            bb += x * w1s[w][(s + moff) * 128 + hh + 64];
        }
        float z1 = a / (1.0f + expf(-bb));
        o0 += z1 * w2s[w][hh * 2];
        o1 += z1 * w2s[w][hh * 2 + 1];
    }
    float zv = o0 / (1.0f + expf(-o1));
    z[(size_t)b * D_ + d] = zv;
    zt[((size_t)b * T_ + (NT - 1)) * D_ + d] = zv;
}

// ---------------- pair-sync update + head + certainty ----------------
__global__ __launch_bounds__(256) void synchead_kernel(const float* __restrict__ z,
                                                       const int* __restrict__ act_l, const int* __restrict__ act_r,
                                                       const int* __restrict__ out_l, const int* __restrict__ out_r,
                                                       const float* __restrict__ raw_a, const float* __restrict__ raw_o,
                                                       const float* __restrict__ head_w, const float* __restrict__ head_b,
                                                       float* __restrict__ a_a, float* __restrict__ b_a, float* __restrict__ s_a,
                                                       float* __restrict__ a_o, float* __restrict__ b_o,
                                                       float* __restrict__ out_logits, float* __restrict__ out_cert, int t) {
    int b = blockIdx.x, tid = threadIdx.x;
    __shared__ float zv[D_];
    __shared__ float red[4][4];
    for (int i = tid; i < D_; i += 256) zv[i] = z[(size_t)b * D_ + i];
    __syncthreads();
    float l0 = 0.f, l1 = 0.f, l2 = 0.f, l3 = 0.f;
    for (int p = tid; p < P_; p += 256) {
        size_t ip = (size_t)b * P_ + p;
        float zl = zv[act_l[p]], zr = zv[act_r[p]];
        float da = 1.0f / (1.0f + expf(raw_a[p]));  // exp(-softplus(x)) = sigmoid(-x)
        float aa = da * a_a[ip] + zl * zr;
        float ba = da * b_a[ip] + 1.0f;
        a_a[ip] = aa; b_a[ip] = ba;
        s_a[ip] = aa / sqrtf(ba + 1e-8f);
        float zlo = zv[out_l[p]], zro = zv[out_r[p]];
        float dz = 1.0f / (1.0f + expf(raw_o[p]));
        float ao = dz * a_o[ip] + zlo * zro;
        float bo = dz * b_o[ip] + 1.0f;
        a_o[ip] = ao; b_o[ip] = bo;
        float so = ao / sqrtf(bo + 1e-8f);
        l0 += so * head_w[p];
        l1 += so * head_w[P_ + p];
        l2 += so * head_w[2 * P_ + p];
        l3 += so * head_w[3 * P_ + p];
    }
    int w = tid >> 6, lane = tid & 63;
#pragma unroll
    for (int off = 32; off >= 1; off >>= 1) {
        l0 += __shfl_xor(l0, off, 64);
        l1 += __shfl_xor(l1, off, 64);
        l2 += __shfl_xor(l2, off, 64);
        l3 += __shfl_xor(l3, off, 64);
    }
    if (lane == 0) { red[w][0] = l0; red[w][1] = l1; red[w][2] = l2; red[w][3] = l3; }
    __syncthreads();
    if (tid == 0) {
        float lg[4];
#pragma unroll
        for (int c = 0; c < 4; c++) {
            lg[c] = red[0][c] + red[1][c] + red[2][c] + red[3][c] + head_b[c];
            out_logits[((size_t)b * C_ + c) * T_ + t] = lg[c];
        }
        float m = fmaxf(fmaxf(lg[0], lg[1]), fmaxf(lg[2], lg[3]));
        float e0 = expf(lg[0] - m), e1 = expf(lg[1] - m), e2 = expf(lg[2] - m), e3 = expf(lg[3] - m);
        float inv = 1.0f / (e0 + e1 + e2 + e3);
        float ent = 0.f, pp;
        pp = fmaxf(e0 * inv, 1e-8f); ent -= pp * logf(pp);
        pp = fmaxf(e1 * inv, 1e-8f); ent -= pp * logf(pp);
        pp = fmaxf(e2 * inv, 1e-8f); ent -= pp * logf(pp);
        pp = fmaxf(e3 * inv, 1e-8f); ent -= pp * logf(pp);
        out_cert[(size_t)b * T_ + t] = 1.0f - ent * (1.0f / 1.3862943611198906f);
    }
}

extern "C" void kernel_launch(void* const* d_in, const int* in_sizes, int n_in,
                              void* d_out, int out_size, void* d_ws, size_t ws_size,
                              hipStream_t stream) {
    const float* kv_tokens  = (const float*)d_in[0];
    const float* raw_r_act  = (const float*)d_in[1];
    const float* raw_r_out  = (const float*)d_in[2];
    const float* q_w        = (const float*)d_in[3];
    const float* q_b        = (const float*)d_in[4];
    const float* in_proj_w  = (const float*)d_in[5];
    const float* in_proj_b  = (const float*)d_in[6];
    const float* out_proj_w = (const float*)d_in[7];
    const float* out_proj_b = (const float*)d_in[8];
    const float* z_ln_g     = (const float*)d_in[9];
    const float* z_ln_b     = (const float*)d_in[10];
    const float* o_ln_g     = (const float*)d_in[11];
    const float* o_ln_b     = (const float*)d_in[12];
    const float* gate_w     = (const float*)d_in[13];
    const float* gate_b     = (const float*)d_in[14];
    const float* cand_w     = (const float*)d_in[15];
    const float* cand_b     = (const float*)d_in[16];
    const float* syn1_w     = (const float*)d_in[17];
    const float* syn1_b     = (const float*)d_in[18];
    const float* syn2_w     = (const float*)d_in[19];
    const float* syn2_b     = (const float*)d_in[20];
    const float* nlm1_w     = (const float*)d_in[21];
    const float* nlm1_b     = (const float*)d_in[22];
    const float* nlm2_w     = (const float*)d_in[23];
    const float* nlm2_b     = (const float*)d_in[24];
    const float* head_w     = (const float*)d_in[25];
    const float* head_b     = (const float*)d_in[26];
    const int* act_l        = (const int*)d_in[27];
    const int* act_r        = (const int*)d_in[28];
    const int* out_l        = (const int*)d_in[29];
    const int* out_r        = (const int*)d_in[30];

    float* out = (float*)d_out;
    float* out_logits = out;                       // [B,C,T]
    float* out_cert = out + B_ * C_ * T_;          // [B,T]
    float* out_zt = out_cert + B_ * T_;            // [B,T,D]

    char* ws = (char*)d_ws;
    size_t off = 0;
    auto alloc = [&](size_t bytes) { void* p = ws + off; off += (bytes + 255) & ~(size_t)255; return p; };
    __hip_bfloat16* kvbuf = (__hip_bfloat16*)alloc((size_t)B_ * N_ * 1024 * 2);
    float* s_a  = (float*)alloc((size_t)B_ * P_ * 4);
    float* a_a  = (float*)alloc((size_t)B_ * P_ * 4);
    float* b_a  = (float*)alloc((size_t)B_ * P_ * 4);
    float* a_o  = (float*)alloc((size_t)B_ * P_ * 4);
    float* b_o  = (float*)alloc((size_t)B_ * P_ * 4);
    float* zbuf = (float*)alloc((size_t)B_ * D_ * 4);
    float* Abuf = (float*)alloc((size_t)T_ * B_ * D_ * 4);
    float* qh   = (float*)alloc((size_t)B_ * E_ * 4);
    float* obuf = (float*)alloc((size_t)B_ * E_ * 4);
    float* ubuf = (float*)alloc((size_t)B_ * 1536 * 4);
    float* fbuf = (float*)alloc((size_t)B_ * 1536 * 4);
    float* tbuf = (float*)alloc((size_t)B_ * HS_ * 4);

    init_kernel<<<512, 256, 0, stream>>>(s_a, a_a, b_a, a_o, b_o, zbuf);
    kvproj_kernel<<<dim3(16, 1024), 256, 0, stream>>>(kv_tokens, in_proj_w, in_proj_b, kvbuf);

    for (int t = 0; t < T_; t++) {
        query_kernel<<<64, 256, 0, stream>>>(s_a, q_w, q_b, in_proj_w, in_proj_b, qh);
        attn_kernel<<<B_ * NH_, 256, 0, stream>>>(kvbuf, qh, obuf);
        oproj_ln_kernel<<<64, 256, 0, stream>>>(obuf, out_proj_w, out_proj_b, o_ln_g, o_ln_b,
                                                zbuf, z_ln_g, z_ln_b, ubuf, fbuf);
        gatecand_kernel<<<64, 256, 0, stream>>>(ubuf, gate_w, gate_b, cand_w, cand_b, fbuf);
        blinear_kernel<1><<<128, 256, 0, stream>>>(fbuf, 1536, 1536, syn1_w, syn1_b, tbuf, HS_);
        blinear_kernel<0><<<64, 256, 0, stream>>>(tbuf, HS_, HS_, syn2_w, syn2_b,
                                                  Abuf + (size_t)t * B_ * D_, D_);
        switch (t) {
            case 0:  nlm_kernel<1><<<256, 256, 0, stream>>>(Abuf, nlm1_w, nlm1_b, nlm2_w, nlm2_b, zbuf, out_zt); break;
            case 1:  nlm_kernel<2><<<256, 256, 0, stream>>>(Abuf, nlm1_w, nlm1_b, nlm2_w, nlm2_b, zbuf, out_zt); break;
            case 2:  nlm_kernel<3><<<256, 256, 0, stream>>>(Abuf, nlm1_w, nlm1_b, nlm2_w, nlm2_b, zbuf, out_zt); break;
            case 3:  nlm_kernel<4><<<256, 256, 0, stream>>>(Abuf, nlm1_w, nlm1_b, nlm2_w, nlm2_b, zbuf, out_zt); break;
            case 4:  nlm_kernel<5><<<256, 256, 0, stream>>>(Abuf, nlm1_w, nlm1_b, nlm2_w, nlm2_b, zbuf, out_zt); break;
            case 5:  nlm_kernel<6><<<256, 256, 0, stream>>>(Abuf, nlm1_w, nlm1_b, nlm2_w, nlm2_b, zbuf, out_zt); break;
            case 6:  nlm_kernel<7><<<256, 256, 0, stream>>>(Abuf, nlm1_w, nlm1_b, nlm2_w, nlm2_b, zbuf, out_zt); break;
            case 7:  nlm_kernel<8><<<256, 256, 0, stream>>>(Abuf, nlm1_w, nlm1_b, nlm2_w, nlm2_b, zbuf, out_zt); break;
            case 8:  nlm_kernel<9><<<256, 256, 0, stream>>>(Abuf, nlm1_w, nlm1_b, nlm2_w, nlm2_b, zbuf, out_zt); break;
            case 9:  nlm_kernel<10><<<256, 256, 0, stream>>>(Abuf, nlm1_w, nlm1_b, nlm2_w, nlm2_b, zbuf, out_zt); break;
            case 10: nlm_kernel<11><<<256, 256, 0, stream>>>(Abuf, nlm1_w, nlm1_b, nlm2_w, nlm2_b, zbuf, out_zt); break;
            default: nlm_kernel<12><<<256, 256, 0, stream>>>(Abuf, nlm1_w, nlm1_b, nlm2_w, nlm2_b, zbuf, out_zt); break;
        }
        synchead_kernel<<<64, 256, 0, stream>>>(zbuf, act_l, act_r, out_l, out_r, raw_r_act, raw_r_out,
                                                head_w, head_b, a_a, b_a, s_a, a_o, b_o,
                                                out_logits, out_cert, t);
    }
}

// Round 2
// 4034.979 us; speedup vs baseline: 1.4865x; 1.4865x over previous
//
#include <hip/hip_runtime.h>
#include <hip/hip_bf16.h>

#define B_ 64
#define N_ 1024
#define E_ 512
#define D_ 1024
#define M_ 16
#define T_ 12
#define P_ 2048
#define HS_ 2048
#define HN_ 64
#define C_ 4
#define NH_ 8
#define DH_ 64

typedef __attribute__((ext_vector_type(8))) short bf16x8;
typedef __attribute__((ext_vector_type(4))) float f32x4;

__device__ __forceinline__ float bf2f(unsigned int u) {
    union { unsigned int i; float f; } c; c.i = (u & 0xffffu) << 16; return c.f;
}
__device__ __forceinline__ unsigned short f2bf(float f) {
    union { float f; unsigned int i; } c; c.f = f;
    unsigned int x = c.i;
    unsigned int r = x + 0x7fffu + ((x >> 16) & 1u);
    return (unsigned short)(r >> 16);
}

// ---------------- init state ----------------
__global__ void init_kernel(unsigned short* s_a_bf, float* a_a, float* b_a, float* a_o, float* b_o, float* z) {
    int i = blockIdx.x * 256 + threadIdx.x;
    if (i < B_ * P_) { a_a[i] = 0.f; b_a[i] = 1.f; a_o[i] = 0.f; b_o[i] = 1.f; }
    if (i < B_ * D_) z[i] = 0.f;
    if (i < 128 * P_) s_a_bf[i] = 0;
}

// ---------------- f32 -> bf16 conversion (vectorized, n multiple of 4) ----------------
__global__ __launch_bounds__(256) void cvt_bf16_kernel(const float* __restrict__ in,
                                                       unsigned short* __restrict__ out, int n4) {
    int i = blockIdx.x * 256 + threadIdx.x;
    if (i < n4) {
        float4 v = ((const float4*)in)[i];
        ushort4 o;
        o.x = f2bf(v.x); o.y = f2bf(v.y); o.z = f2bf(v.z); o.w = f2bf(v.w);
        ((ushort4*)out)[i] = o;
    }
}

// ---------------- transpose + cvt: out[c][r] = bf16(in[r][c]) ----------------
__global__ __launch_bounds__(256) void transpose_cvt_kernel(const float* __restrict__ in,
                                                            unsigned short* __restrict__ out,
                                                            int R, int Ccols) {
    __shared__ float tb[32][33];
    int c0 = blockIdx.x * 32, r0 = blockIdx.y * 32;
    int tx = threadIdx.x & 31, ty = threadIdx.x >> 5;
#pragma unroll
    for (int i = 0; i < 32; i += 8) tb[ty + i][tx] = in[(size_t)(r0 + ty + i) * Ccols + c0 + tx];
    __syncthreads();
#pragma unroll
    for (int i = 0; i < 32; i += 8) out[(size_t)(c0 + ty + i) * R + r0 + tx] = f2bf(tb[tx][ty + i]);
}

// ---------------- combined query bias: bc[e] = sum_k Wq[e][k]*q_b[k] + bq[e] ----------------
__global__ __launch_bounds__(256) void bcomb_kernel(const float* __restrict__ in_proj_w,
                                                    const float* __restrict__ in_proj_b,
                                                    const float* __restrict__ q_b,
                                                    float* __restrict__ bc) {
    int e = blockIdx.x * 256 + threadIdx.x;
    if (e < E_) {
        const float* wr = in_proj_w + (size_t)e * E_;
        float s = in_proj_b[e];
        for (int k = 0; k < E_; k += 4) {
            float4 w4 = *(const float4*)(wr + k);
            float4 q4 = *(const float4*)(q_b + k);
            s += w4.x * q4.x + w4.y * q4.y + w4.z * q4.z + w4.w * q4.w;
        }
        bc[e] = s;
    }
}

// ---------------- bf16 MFMA GEMM: C[M][N] = A[M][K] * Bt[N][K]^T (+bias[N]), bf16 out ----------------
// 128x128 tile, BK=32, 4 waves (2x2), double-buffered LDS via global_load_lds w16,
// counted vmcnt(4) + raw barriers, XOR k-group swizzle (both-sides, rule #21).
template <bool HAS_BIAS>
__global__ __launch_bounds__(256) void gemm_bt_kernel(const unsigned short* __restrict__ A,
                                                      const unsigned short* __restrict__ Bt,
                                                      const float* __restrict__ bias,
                                                      unsigned short* __restrict__ C,
                                                      int M, int N, int K) {
    __shared__ __align__(16) unsigned short ldsA[2][4096];
    __shared__ __align__(16) unsigned short ldsB[2][4096];
    int m0 = blockIdx.y * 128;
    int n0 = blockIdx.x * 128;
    int tid = threadIdx.x;
    int wv = tid >> 6, l = tid & 63;
    int wr = wv >> 1, wc = wv & 1;
    int lr = l & 15, lg = l >> 4;
    f32x4 acc[4][4] = {};

    auto stage = [&](int buf, int kt) {
        int k0 = kt * 32;
#pragma unroll
        for (int i = 0; i < 2; i++) {
            int tsk = tid + 256 * i;
            int r = tsk >> 2, g = tsk & 3;
            int gs = (g ^ (r & 3)) * 8;
            __builtin_amdgcn_global_load_lds(
                (const __attribute__((address_space(1))) void*)(A + (size_t)(m0 + r) * K + k0 + gs),
                (__attribute__((address_space(3))) void*)&ldsA[buf][tsk * 8], 16, 0, 0);
        }
#pragma unroll
        for (int i = 0; i < 2; i++) {
            int tsk = tid + 256 * i;
            int r = tsk >> 2, g = tsk & 3;
            int gs = (g ^ (r & 3)) * 8;
            __builtin_amdgcn_global_load_lds(
                (const __attribute__((address_space(1))) void*)(Bt + (size_t)(n0 + r) * K + k0 + gs),
                (__attribute__((address_space(3))) void*)&ldsB[buf][tsk * 8], 16, 0, 0);
        }
    };

    int nt = K >> 5;
    stage(0, 0);
    for (int t = 0; t < nt; t++) {
        int cur = t & 1;
        if (t + 1 < nt) {
            stage(cur ^ 1, t + 1);
            asm volatile("s_waitcnt vmcnt(4)" ::: "memory");
        } else {
            asm volatile("s_waitcnt vmcnt(0)" ::: "memory");
        }
        __builtin_amdgcn_s_barrier();
        bf16x8 af[4], bfr[4];
#pragma unroll
        for (int mi = 0; mi < 4; mi++) {
            int r = wr * 64 + mi * 16 + lr;
            af[mi] = *(const bf16x8*)&ldsA[cur][r * 32 + ((lg ^ (r & 3)) << 3)];
        }
#pragma unroll
        for (int ni = 0; ni < 4; ni++) {
            int c = wc * 64 + ni * 16 + lr;
            bfr[ni] = *(const bf16x8*)&ldsB[cur][c * 32 + ((lg ^ (c & 3)) << 3)];
        }
#pragma unroll
        for (int mi = 0; mi < 4; mi++)
#pragma unroll
            for (int ni = 0; ni < 4; ni++)
                acc[mi][ni] = __builtin_amdgcn_mfma_f32_16x16x32_bf16(af[mi], bfr[ni], acc[mi][ni], 0, 0, 0);
        __builtin_amdgcn_s_barrier();
    }
#pragma unroll
    for (int ni = 0; ni < 4; ni++) {
        int col = n0 + wc * 64 + ni * 16 + lr;
        float bv = HAS_BIAS ? bias[col] : 0.0f;
#pragma unroll
        for (int mi = 0; mi < 4; mi++) {
            int row = m0 + wr * 64 + mi * 16 + lg * 4;
#pragma unroll
            for (int r = 0; r < 4; r++) {
                C[(size_t)(row + r) * N + col] = f2bf(acc[mi][ni][r] + bv);
            }
        }
    }
}

// ---------------- wave reduce helpers ----------------
__device__ __forceinline__ float wave_max64(float v) {
#pragma unroll
    for (int off = 32; off >= 1; off >>= 1) v = fmaxf(v, __shfl_xor(v, off, 64));
    return v;
}
__device__ __forceinline__ float wave_sum64(float v) {
#pragma unroll
    for (int off = 32; off >= 1; off >>= 1) v += __shfl_xor(v, off, 64);
    return v;
}

// ---------------- attention for one (b,h): scores->softmax->o ----------------
__global__ __launch_bounds__(256) void attn_kernel(const unsigned short* __restrict__ kvbuf,
                                                   const unsigned short* __restrict__ qh,
                                                   float* __restrict__ o) {
    int bh = blockIdx.x;
    int b = bh >> 3, h = bh & 7;
    __shared__ float sc[N_];
    __shared__ float qv[DH_];
    __shared__ float red[8];
    __shared__ float opart[4][DH_];
    int tid = threadIdx.x;
    int w = tid >> 6, lane = tid & 63;
    if (tid < DH_) qv[tid] = bf2f(qh[(size_t)b * E_ + h * DH_ + tid]);
    __syncthreads();
    const unsigned short* kb = kvbuf + (size_t)b * N_ * 1024 + h * DH_;
    float myv[4];
#pragma unroll
    for (int i = 0; i < 4; i++) {
        int n = tid + i * 256;
        const unsigned short* kr = kb + (size_t)n * 1024;
        float s = 0.f;
#pragma unroll
        for (int d = 0; d < DH_; d += 8) {
            uint4 pk = *(const uint4*)(kr + d);
            s += bf2f(pk.x) * qv[d + 0] + bf2f(pk.x >> 16) * qv[d + 1]
               + bf2f(pk.y) * qv[d + 2] + bf2f(pk.y >> 16) * qv[d + 3]
               + bf2f(pk.z) * qv[d + 4] + bf2f(pk.z >> 16) * qv[d + 5]
               + bf2f(pk.w) * qv[d + 6] + bf2f(pk.w >> 16) * qv[d + 7];
        }
        myv[i] = s * 0.125f;  // 1/sqrt(64)
    }
    float m = fmaxf(fmaxf(myv[0], myv[1]), fmaxf(myv[2], myv[3]));
    m = wave_max64(m);
    if (lane == 0) red[w] = m;
    __syncthreads();
    m = fmaxf(fmaxf(red[0], red[1]), fmaxf(red[2], red[3]));
    float s = 0.f;
#pragma unroll
    for (int i = 0; i < 4; i++) {
        float e = expf(myv[i] - m);
        sc[tid + i * 256] = e;
        s += e;
    }
    s = wave_sum64(s);
    if (lane == 0) red[4 + w] = s;
    __syncthreads();
    float inv = 1.0f / (red[4] + red[5] + red[6] + red[7]);
    const unsigned short* vb = kvbuf + (size_t)b * N_ * 1024 + E_ + h * DH_;
    float a0 = 0.f, a1 = 0.f;
    int n0 = w * 256;
    for (int i = 0; i < 256; i += 2) {
        a0 += sc[n0 + i]     * bf2f(vb[(size_t)(n0 + i)     * 1024 + lane]);
        a1 += sc[n0 + i + 1] * bf2f(vb[(size_t)(n0 + i + 1) * 1024 + lane]);
    }
    opart[w][lane] = a0 + a1;
    __syncthreads();
    if (tid < DH_) {
        float r = (opart[0][tid] + opart[1][tid] + opart[2][tid] + opart[3][tid]) * inv;
        o[(size_t)b * E_ + h * DH_ + tid] = r;
    }
}

// ---------------- out_proj + LN(o) + LN(z): fill u=[zn, o_ln], fused[., 1024:]=o_ln ----------------
__global__ __launch_bounds__(256) void oproj_ln_kernel(const float* __restrict__ o_attn,
                                                       const float* __restrict__ Wout,
                                                       const float* __restrict__ bout,
                                                       const float* __restrict__ og,
                                                       const float* __restrict__ obv,
                                                       const float* __restrict__ z,
                                                       const float* __restrict__ zg,
                                                       const float* __restrict__ zbv,
                                                       float* __restrict__ u,
                                                       float* __restrict__ fused) {
    int b = blockIdx.x, tid = threadIdx.x;
    __shared__ float ov[E_];
    __shared__ float red[16];
    for (int e = tid; e < E_; e += 256) ov[e] = o_attn[(size_t)b * E_ + e];
    __syncthreads();
    float v[2];
#pragma unroll
    for (int i = 0; i < 2; i++) {
        int e = tid + i * 256;
        const float* wr = Wout + (size_t)e * E_;
        float acc = 0.f;
        for (int k = 0; k < E_; k += 4) {
            float4 wv = *(const float4*)(wr + k);
            acc += wv.x * ov[k] + wv.y * ov[k + 1] + wv.z * ov[k + 2] + wv.w * ov[k + 3];
        }
        v[i] = acc + bout[e];
    }
    int w = tid >> 6, lane = tid & 63;
    float s1 = v[0] + v[1];
    float s2 = v[0] * v[0] + v[1] * v[1];
#pragma unroll
    for (int off = 32; off >= 1; off >>= 1) { s1 += __shfl_xor(s1, off, 64); s2 += __shfl_xor(s2, off, 64); }
    if (lane == 0) { red[w] = s1; red[4 + w] = s2; }
    __syncthreads();
    s1 = red[0] + red[1] + red[2] + red[3];
    s2 = red[4] + red[5] + red[6] + red[7];
    float mean = s1 * (1.0f / 512.0f);
    float var = s2 * (1.0f / 512.0f) - mean * mean;
    float rstd = 1.0f / sqrtf(var + 1e-5f);
#pragma unroll
    for (int i = 0; i < 2; i++) {
        int e = tid + i * 256;
        float val = (v[i] - mean) * rstd * og[e] + obv[e];
        u[(size_t)b * 1536 + D_ + e] = val;
        fused[(size_t)b * 1536 + D_ + e] = val;
    }
    float zl[4];
    float t1 = 0.f, t2 = 0.f;
#pragma unroll
    for (int i = 0; i < 4; i++) {
        int d = tid + i * 256;
        zl[i] = z[(size_t)b * D_ + d];
        t1 += zl[i]; t2 += zl[i] * zl[i];
    }
#pragma unroll
    for (int off = 32; off >= 1; off >>= 1) { t1 += __shfl_xor(t1, off, 64); t2 += __shfl_xor(t2, off, 64); }
    __syncthreads();
    if (lane == 0) { red[8 + w] = t1; red[12 + w] = t2; }
    __syncthreads();
    t1 = red[8] + red[9] + red[10] + red[11];
    t2 = red[12] + red[13] + red[14] + red[15];
    float zmean = t1 * (1.0f / 1024.0f);
    float zvar = t2 * (1.0f / 1024.0f) - zmean * zmean;
    float zr = 1.0f / sqrtf(zvar + 1e-5f);
#pragma unroll
    for (int i = 0; i < 4; i++) {
        int d = tid + i * 256;
        u[(size_t)b * 1536 + d] = (zl[i] - zmean) * zr * zg[d] + zbv[d];
    }
}

// ---------------- gate + cand + z_bar: fused[., 0:1024] = (1-g)*zn + g*h ----------------
__global__ __launch_bounds__(256) void gatecand_kernel(const float* __restrict__ u,
                                                       const float* __restrict__ gate_w,
                                                       const float* __restrict__ gate_b,
                                                       const float* __restrict__ cand_w,
                                                       const float* __restrict__ cand_b,
                                                       float* __restrict__ fused) {
    __shared__ float inT[32][68];
    __shared__ float Wg[16][33];
    __shared__ float Wc[16][33];
    int j0 = blockIdx.x * 16;
    int tid = threadIdx.x;
    int tj = tid & 15;
    int tb4 = (tid >> 4) << 2;
    int lb = tid >> 2;
    int lc = (tid & 3) << 2;
    int jr = tid >> 4;
    int c2 = (tid & 15) << 1;
    float accg[4] = {}, accc[4] = {};
    for (int k0 = 0; k0 < 1536; k0 += 32) {
        float4 x0 = *(const float4*)(u + (size_t)lb * 1536 + k0 + lc);
        float4 x1 = *(const float4*)(u + (size_t)lb * 1536 + k0 + lc + 16);
        inT[lc + 0][lb] = x0.x; inT[lc + 1][lb] = x0.y; inT[lc + 2][lb] = x0.z; inT[lc + 3][lb] = x0.w;
        inT[lc + 16][lb] = x1.x; inT[lc + 17][lb] = x1.y; inT[lc + 18][lb] = x1.z; inT[lc + 19][lb] = x1.w;
        float2 wg = *(const float2*)(gate_w + (size_t)(j0 + jr) * 1536 + k0 + c2);
        Wg[jr][c2] = wg.x; Wg[jr][c2 + 1] = wg.y;
        float2 wc = *(const float2*)(cand_w + (size_t)(j0 + jr) * 1536 + k0 + c2);
        Wc[jr][c2] = wc.x; Wc[jr][c2 + 1] = wc.y;
        __syncthreads();
#pragma unroll
        for (int kk = 0; kk < 32; kk++) {
            float4 a = *(const float4*)&inT[kk][tb4];
            float vg = Wg[tj][kk], vc = Wc[tj][kk];
            accg[0] += a.x * vg; accg[1] += a.y * vg; accg[2] += a.z * vg; accg[3] += a.w * vg;
            accc[0] += a.x * vc; accc[1] += a.y * vc; accc[2] += a.z * vc; accc[3] += a.w * vc;
        }
        __syncthreads();
    }
    int j = j0 + tj;
    float gb = gate_b[j], cb = cand_b[j];
#pragma unroll
    for (int i = 0; i < 4; i++) {
        int b = tb4 + i;
        float g = 1.0f / (1.0f + expf(-(accg[i] + gb)));
        float hh = tanhf(accc[i] + cb);
        float zn = u[(size_t)b * 1536 + j];
        fused[(size_t)b * 1536 + j] = (1.0f - g) * zn + g * hh;
    }
}

// ---------------- generic batch-64 linear ----------------
template <int ACT>
__global__ __launch_bounds__(256) void blinear_kernel(const float* __restrict__ in, int in_stride, int K,
                                                      const float* __restrict__ W,
                                                      const float* __restrict__ bias,
                                                      float* __restrict__ out, int out_stride) {
    __shared__ float inT[32][68];
    __shared__ float Wt[16][33];
    int j0 = blockIdx.x * 16;
    int tid = threadIdx.x;
    int tj = tid & 15;
    int tb4 = (tid >> 4) << 2;
    int lb = tid >> 2;
    int lc = (tid & 3) << 2;
    int jr = tid >> 4;
    int c2 = (tid & 15) << 1;
    float acc[4] = {};
    for (int k0 = 0; k0 < K; k0 += 32) {
        float4 x0 = *(const float4*)(in + (size_t)lb * in_stride + k0 + lc);
        float4 x1 = *(const float4*)(in + (size_t)lb * in_stride + k0 + lc + 16);
        inT[lc + 0][lb] = x0.x; inT[lc + 1][lb] = x0.y; inT[lc + 2][lb] = x0.z; inT[lc + 3][lb] = x0.w;
        inT[lc + 16][lb] = x1.x; inT[lc + 17][lb] = x1.y; inT[lc + 18][lb] = x1.z; inT[lc + 19][lb] = x1.w;
        float2 wv = *(const float2*)(W + (size_t)(j0 + jr) * K + k0 + c2);
        Wt[jr][c2] = wv.x; Wt[jr][c2 + 1] = wv.y;
        __syncthreads();
#pragma unroll
        for (int kk = 0; kk < 32; kk++) {
            float4 a = *(const float4*)&inT[kk][tb4];
            float wval = Wt[tj][kk];
            acc[0] += a.x * wval; acc[1] += a.y * wval; acc[2] += a.z * wval; acc[3] += a.w * wval;
        }
        __syncthreads();
    }
    int j = j0 + tj;
    float bj = bias[j];
#pragma unroll
    for (int i = 0; i < 4; i++) {
        float val = acc[i] + bj;
        if (ACT == 1) val = 0.5f * val * (1.0f + erff(val * 0.70710678118654752f));
        out[(size_t)(tb4 + i) * out_stride + j] = val;
    }
}

// ---------------- NLM (per-neuron 2-layer GLU MLP over A history) ----------------
template <int NT>
__global__ __launch_bounds__(256) void nlm_kernel(const float* __restrict__ Abuf,
                                                  const float* __restrict__ w1g,
                                                  const float* __restrict__ b1g,
                                                  const float* __restrict__ w2g,
                                                  const float* __restrict__ b2g,
                                                  float* __restrict__ z,
                                                  float* __restrict__ zt) {
    __shared__ float w1s[4][2048];
    __shared__ float b1s[4][128];
    __shared__ float w2s[4][128];
    __shared__ float b2s[4][2];
    int tid = threadIdx.x;
    int w = tid >> 6, lane = tid & 63;
    int d = blockIdx.x * 4 + w;
    for (int i = lane; i < 2048; i += 64) w1s[w][i] = w1g[(size_t)d * 2048 + i];
    for (int i = lane; i < 128; i += 64) {
        b1s[w][i] = b1g[(size_t)d * 128 + i];
        w2s[w][i] = w2g[(size_t)d * 128 + i];
    }
    if (lane < 2) b2s[w][lane] = b2g[d * 2 + lane];
    __syncthreads();
    const int b = lane;
    float av[NT];
#pragma unroll
    for (int s = 0; s < NT; s++) av[s] = Abuf[(size_t)s * (B_ * D_) + (size_t)b * D_ + d];
    constexpr int moff = M_ - NT;
    float o0 = b2s[w][0], o1 = b2s[w][1];
    for (int hh = 0; hh < 64; hh++) {
        float a = b1s[w][hh], bb = b1s[w][hh + 64];
#pragma unroll
        for (int s = 0; s < NT; s++) {
            float x = av[s];
            a += x * w1s[w][(s + moff) * 128 + hh];
            bb += x * w1s[w][(s + moff) * 128 + hh + 64];
        }
        float z1 = a / (1.0f + expf(-bb));
        o0 += z1 * w2s[w][hh * 2];
        o1 += z1 * w2s[w][hh * 2 + 1];
    }
    float zv = o0 / (1.0f + expf(-o1));
    z[(size_t)b * D_ + d] = zv;
    zt[((size_t)b * T_ + (NT - 1)) * D_ + d] = zv;
}

// ---------------- pair-sync update + head + certainty ----------------
__global__ __launch_bounds__(256) void synchead_kernel(const float* __restrict__ z,
                                                       const int* __restrict__ act_l, const int* __restrict__ act_r,
                                                       const int* __restrict__ out_l, const int* __restrict__ out_r,
                                                       const float* __restrict__ raw_a, const float* __restrict__ raw_o,
                                                       const float* __restrict__ head_w, const float* __restrict__ head_b,
                                                       float* __restrict__ a_a, float* __restrict__ b_a,
                                                       unsigned short* __restrict__ s_a_bf,
                                                       float* __restrict__ a_o, float* __restrict__ b_o,
                                                       float* __restrict__ out_logits, float* __restrict__ out_cert, int t) {
    int b = blockIdx.x, tid = threadIdx.x;
    __shared__ float zv[D_];
    __shared__ float red[4][4];
    for (int i = tid; i < D_; i += 256) zv[i] = z[(size_t)b * D_ + i];
    __syncthreads();
    float l0 = 0.f, l1 = 0.f, l2 = 0.f, l3 = 0.f;
    for (int p = tid; p < P_; p += 256) {
        size_t ip = (size_t)b * P_ + p;
        float zl = zv[act_l[p]], zr = zv[act_r[p]];
        float da = 1.0f / (1.0f + expf(raw_a[p]));
        float aa = da * a_a[ip] + zl * zr;
        float ba = da * b_a[ip] + 1.0f;
        a_a[ip] = aa; b_a[ip] = ba;
        s_a_bf[(size_t)b * P_ + p] = f2bf(aa / sqrtf(ba + 1e-8f));
        float zlo = zv[out_l[p]], zro = zv[out_r[p]];
        float dz = 1.0f / (1.0f + expf(raw_o[p]));
        float ao = dz * a_o[ip] + zlo * zro;
        float bo = dz * b_o[ip] + 1.0f;
        a_o[ip] = ao; b_o[ip] = bo;
        float so = ao / sqrtf(bo + 1e-8f);
        l0 += so * head_w[p];
        l1 += so * head_w[P_ + p];
        l2 += so * head_w[2 * P_ + p];
        l3 += so * head_w[3 * P_ + p];
    }
    int w = tid >> 6, lane = tid & 63;
#pragma unroll
    for (int off = 32; off >= 1; off >>= 1) {
        l0 += __shfl_xor(l0, off, 64);
        l1 += __shfl_xor(l1, off, 64);
        l2 += __shfl_xor(l2, off, 64);
        l3 += __shfl_xor(l3, off, 64);
    }
    if (lane == 0) { red[w][0] = l0; red[w][1] = l1; red[w][2] = l2; red[w][3] = l3; }
    __syncthreads();
    if (tid == 0) {
        float lg[4];
#pragma unroll
        for (int c = 0; c < 4; c++) {
            lg[c] = red[0][c] + red[1][c] + red[2][c] + red[3][c] + head_b[c];
            out_logits[((size_t)b * C_ + c) * T_ + t] = lg[c];
        }
        float m = fmaxf(fmaxf(lg[0], lg[1]), fmaxf(lg[2], lg[3]));
        float e0 = expf(lg[0] - m), e1 = expf(lg[1] - m), e2 = expf(lg[2] - m), e3 = expf(lg[3] - m);
        float inv = 1.0f / (e0 + e1 + e2 + e3);
        float ent = 0.f, pp;
        pp = fmaxf(e0 * inv, 1e-8f); ent -= pp * logf(pp);
        pp = fmaxf(e1 * inv, 1e-8f); ent -= pp * logf(pp);
        pp = fmaxf(e2 * inv, 1e-8f); ent -= pp * logf(pp);
        pp = fmaxf(e3 * inv, 1e-8f); ent -= pp * logf(pp);
        out_cert[(size_t)b * T_ + t] = 1.0f - ent * (1.0f / 1.3862943611198906f);
    }
}

extern "C" void kernel_launch(void* const* d_in, const int* in_sizes, int n_in,
                              void* d_out, int out_size, void* d_ws, size_t ws_size,
                              hipStream_t stream) {
    const float* kv_tokens  = (const float*)d_in[0];
    const float* raw_r_act  = (const float*)d_in[1];
    const float* raw_r_out  = (const float*)d_in[2];
    const float* q_w        = (const float*)d_in[3];
    const float* q_b        = (const float*)d_in[4];
    const float* in_proj_w  = (const float*)d_in[5];
    const float* in_proj_b  = (const float*)d_in[6];
    const float* out_proj_w = (const float*)d_in[7];
    const float* out_proj_b = (const float*)d_in[8];
    const float* z_ln_g     = (const float*)d_in[9];
    const float* z_ln_b     = (const float*)d_in[10];
    const float* o_ln_g     = (const float*)d_in[11];
    const float* o_ln_b     = (const float*)d_in[12];
    const float* gate_w     = (const float*)d_in[13];
    const float* gate_b     = (const float*)d_in[14];
    const float* cand_w     = (const float*)d_in[15];
    const float* cand_b     = (const float*)d_in[16];
    const float* syn1_w     = (const float*)d_in[17];
    const float* syn1_b     = (const float*)d_in[18];
    const float* syn2_w     = (const float*)d_in[19];
    const float* syn2_b     = (const float*)d_in[20];
    const float* nlm1_w     = (const float*)d_in[21];
    const float* nlm1_b     = (const float*)d_in[22];
    const float* nlm2_w     = (const float*)d_in[23];
    const float* nlm2_b     = (const float*)d_in[24];
    const float* head_w     = (const float*)d_in[25];
    const float* head_b     = (const float*)d_in[26];
    const int* act_l        = (const int*)d_in[27];
    const int* act_r        = (const int*)d_in[28];
    const int* out_l        = (const int*)d_in[29];
    const int* out_r        = (const int*)d_in[30];

    float* out = (float*)d_out;
    float* out_logits = out;                       // [B,C,T]
    float* out_cert = out + B_ * C_ * T_;          // [B,T]
    float* out_zt = out_cert + B_ * T_;            // [B,T,D]

    char* ws = (char*)d_ws;
    size_t off = 0;
    auto alloc = [&](size_t bytes) { void* p = ws + off; off += (bytes + 255) & ~(size_t)255; return p; };
    unsigned short* kvbuf   = (unsigned short*)alloc((size_t)B_ * N_ * 1024 * 2);   // 128MB: [b][n][k512|v512] bf16
    unsigned short* kvch_bf = (unsigned short*)alloc((size_t)4096 * E_ * 2);        // 4MB chunk of kv in bf16
    unsigned short* Wkv_bf  = (unsigned short*)alloc((size_t)1024 * E_ * 2);
    unsigned short* Wq_bf   = (unsigned short*)alloc((size_t)E_ * E_ * 2);
    unsigned short* qwT_bf  = (unsigned short*)alloc((size_t)P_ * E_ * 2);
    unsigned short* Wc_bf   = (unsigned short*)alloc((size_t)E_ * P_ * 2);
    float* b_comb = (float*)alloc(E_ * 4);
    unsigned short* s_a_bf = (unsigned short*)alloc((size_t)128 * P_ * 2);
    unsigned short* qh_bf  = (unsigned short*)alloc((size_t)128 * E_ * 2);
    float* a_a  = (float*)alloc((size_t)B_ * P_ * 4);
    float* b_a  = (float*)alloc((size_t)B_ * P_ * 4);
    float* a_o  = (float*)alloc((size_t)B_ * P_ * 4);
    float* b_o  = (float*)alloc((size_t)B_ * P_ * 4);
    float* zbuf = (float*)alloc((size_t)B_ * D_ * 4);
    float* Abuf = (float*)alloc((size_t)T_ * B_ * D_ * 4);
    float* obuf = (float*)alloc((size_t)B_ * E_ * 4);
    float* ubuf = (float*)alloc((size_t)B_ * 1536 * 4);
    float* fbuf = (float*)alloc((size_t)B_ * 1536 * 4);
    float* tbuf = (float*)alloc((size_t)B_ * HS_ * 4);

    init_kernel<<<1024, 256, 0, stream>>>(s_a_bf, a_a, b_a, a_o, b_o, zbuf);

    // --- one-time weight prep ---
    cvt_bf16_kernel<<<(1024 * E_ / 4 + 255) / 256, 256, 0, stream>>>(in_proj_w + (size_t)E_ * E_, Wkv_bf, 1024 * E_ / 4);
    cvt_bf16_kernel<<<(E_ * E_ / 4 + 255) / 256, 256, 0, stream>>>(in_proj_w, Wq_bf, E_ * E_ / 4);
    transpose_cvt_kernel<<<dim3(P_ / 32, E_ / 32), 256, 0, stream>>>(q_w, qwT_bf, E_, P_);
    bcomb_kernel<<<2, 256, 0, stream>>>(in_proj_w, in_proj_b, q_b, b_comb);
    // Wc = Wq @ q_w : A=Wq_bf [512][512], Bt=qwT_bf [2048][512] -> Wc [512][2048]
    gemm_bt_kernel<false><<<dim3(P_ / 128, E_ / 128), 256, 0, stream>>>(Wq_bf, qwT_bf, nullptr, Wc_bf, E_, P_, E_);

    // --- KV projection (chunked cvt + MFMA GEMM) ---
    for (int ch = 0; ch < 16; ch++) {
        const float* src = kv_tokens + (size_t)ch * 4096 * E_;
        cvt_bf16_kernel<<<(4096 * E_ / 4) / 256, 256, 0, stream>>>(src, kvch_bf, 4096 * E_ / 4);
        gemm_bt_kernel<true><<<dim3(8, 32), 256, 0, stream>>>(kvch_bf, Wkv_bf, in_proj_b + E_,
                                                              kvbuf + (size_t)ch * 4096 * 1024, 4096, 1024, E_);
    }

    for (int t = 0; t < T_; t++) {
        // qh = s_a @ Wc^T + b_comb   (M=128 padded, N=512, K=2048)
        gemm_bt_kernel<true><<<dim3(4, 1), 256, 0, stream>>>(s_a_bf, Wc_bf, b_comb, qh_bf, 128, E_, P_);
        attn_kernel<<<B_ * NH_, 256, 0, stream>>>(kvbuf, qh_bf, obuf);
        oproj_ln_kernel<<<64, 256, 0, stream>>>(obuf, out_proj_w, out_proj_b, o_ln_g, o_ln_b,
                                                zbuf, z_ln_g, z_ln_b, ubuf, fbuf);
        gatecand_kernel<<<64, 256, 0, stream>>>(ubuf, gate_w, gate_b, cand_w, cand_b, fbuf);
        blinear_kernel<1><<<128, 256, 0, stream>>>(fbuf, 1536, 1536, syn1_w, syn1_b, tbuf, HS_);
        blinear_kernel<0><<<64, 256, 0, stream>>>(tbuf, HS_, HS_, syn2_w, syn2_b,
                                                  Abuf + (size_t)t * B_ * D_, D_);
        switch (t) {
            case 0:  nlm_kernel<1><<<256, 256, 0, stream>>>(Abuf, nlm1_w, nlm1_b, nlm2_w, nlm2_b, zbuf, out_zt); break;
            case 1:  nlm_kernel<2><<<256, 256, 0, stream>>>(Abuf, nlm1_w, nlm1_b, nlm2_w, nlm2_b, zbuf, out_zt); break;
            case 2:  nlm_kernel<3><<<256, 256, 0, stream>>>(Abuf, nlm1_w, nlm1_b, nlm2_w, nlm2_b, zbuf, out_zt); break;
            case 3:  nlm_kernel<4><<<256, 256, 0, stream>>>(Abuf, nlm1_w, nlm1_b, nlm2_w, nlm2_b, zbuf, out_zt); break;
            case 4:  nlm_kernel<5><<<256, 256, 0, stream>>>(Abuf, nlm1_w, nlm1_b, nlm2_w, nlm2_b, zbuf, out_zt); break;
            case 5:  nlm_kernel<6><<<256, 256, 0, stream>>>(Abuf, nlm1_w, nlm1_b, nlm2_w, nlm2_b, zbuf, out_zt); break;
            case 6:  nlm_kernel<7><<<256, 256, 0, stream>>>(Abuf, nlm1_w, nlm1_b, nlm2_w, nlm2_b, zbuf, out_zt); break;
            case 7:  nlm_kernel<8><<<256, 256, 0, stream>>>(Abuf, nlm1_w, nlm1_b, nlm2_w, nlm2_b, zbuf, out_zt); break;
            case 8:  nlm_kernel<9><<<256, 256, 0, stream>>>(Abuf, nlm1_w, nlm1_b, nlm2_w, nlm2_b, zbuf, out_zt); break;
            case 9:  nlm_kernel<10><<<256, 256, 0, stream>>>(Abuf, nlm1_w, nlm1_b, nlm2_w, nlm2_b, zbuf, out_zt); break;
            case 10: nlm_kernel<11><<<256, 256, 0, stream>>>(Abuf, nlm1_w, nlm1_b, nlm2_w, nlm2_b, zbuf, out_zt); break;
            default: nlm_kernel<12><<<256, 256, 0, stream>>>(Abuf, nlm1_w, nlm1_b, nlm2_w, nlm2_b, zbuf, out_zt); break;
        }
        synchead_kernel<<<64, 256, 0, stream>>>(zbuf, act_l, act_r, out_l, out_r, raw_r_act, raw_r_out,
                                                head_w, head_b, a_a, b_a, s_a_bf, a_o, b_o,
                                                out_logits, out_cert, t);
    }
}

// Round 3
// 1915.913 us; speedup vs baseline: 3.1307x; 2.1060x over previous
//
#include <hip/hip_runtime.h>
#include <hip/hip_bf16.h>

#define B_ 64
#define N_ 1024
#define E_ 512
#define D_ 1024
#define M_ 16
#define T_ 12
#define P_ 2048
#define HS_ 2048
#define HN_ 64
#define C_ 4
#define NH_ 8
#define DH_ 64

typedef __attribute__((ext_vector_type(8))) short bf16x8;
typedef __attribute__((ext_vector_type(4))) float f32x4;

__device__ __forceinline__ float bf2f(unsigned int u) {
    union { unsigned int i; float f; } c; c.i = (u & 0xffffu) << 16; return c.f;
}
__device__ __forceinline__ unsigned short f2bf(float f) {
    union { float f; unsigned int i; } c; c.f = f;
    unsigned int x = c.i;
    unsigned int r = x + 0x7fffu + ((x >> 16) & 1u);
    return (unsigned short)(r >> 16);
}

// ---------------- init state ----------------
__global__ void init_kernel(unsigned short* s_a_bf, float* a_a, float* b_a, float* a_o, float* b_o, float* z) {
    int i = blockIdx.x * 256 + threadIdx.x;
    if (i < B_ * P_) { a_a[i] = 0.f; b_a[i] = 1.f; a_o[i] = 0.f; b_o[i] = 1.f; s_a_bf[i] = 0; }
    if (i < B_ * D_) z[i] = 0.f;
}

// ---------------- f32 -> bf16 conversion (vectorized, n multiple of 4) ----------------
__global__ __launch_bounds__(256) void cvt_bf16_kernel(const float* __restrict__ in,
                                                       unsigned short* __restrict__ out, int n4) {
    int i = blockIdx.x * 256 + threadIdx.x;
    if (i < n4) {
        float4 v = ((const float4*)in)[i];
        ushort4 o;
        o.x = f2bf(v.x); o.y = f2bf(v.y); o.z = f2bf(v.z); o.w = f2bf(v.w);
        ((ushort4*)out)[i] = o;
    }
}

// ---------------- transpose + cvt: out[c][r] = bf16(in[r][c]) ----------------
__global__ __launch_bounds__(256) void transpose_cvt_kernel(const float* __restrict__ in,
                                                            unsigned short* __restrict__ out,
                                                            int R, int Ccols) {
    __shared__ float tb[32][33];
    int c0 = blockIdx.x * 32, r0 = blockIdx.y * 32;
    int tx = threadIdx.x & 31, ty = threadIdx.x >> 5;
#pragma unroll
    for (int i = 0; i < 32; i += 8) tb[ty + i][tx] = in[(size_t)(r0 + ty + i) * Ccols + c0 + tx];
    __syncthreads();
#pragma unroll
    for (int i = 0; i < 32; i += 8) out[(size_t)(c0 + ty + i) * R + r0 + tx] = f2bf(tb[tx][ty + i]);
}

// ---------------- combined query bias: bc[e] = sum_k Wq[e][k]*q_b[k] + bq[e] ----------------
__global__ __launch_bounds__(256) void bcomb_kernel(const float* __restrict__ in_proj_w,
                                                    const float* __restrict__ in_proj_b,
                                                    const float* __restrict__ q_b,
                                                    float* __restrict__ bc) {
    int e = blockIdx.x * 256 + threadIdx.x;
    if (e < E_) {
        const float* wr = in_proj_w + (size_t)e * E_;
        float s = in_proj_b[e];
        for (int k = 0; k < E_; k += 4) {
            float4 w4 = *(const float4*)(wr + k);
            float4 q4 = *(const float4*)(q_b + k);
            s += w4.x * q4.x + w4.y * q4.y + w4.z * q4.z + w4.w * q4.w;
        }
        bc[e] = s;
    }
}

// ---------------- big bf16 MFMA GEMM (128x128 tile): C = A*Bt^T (+bias), bf16 out ----------------
template <bool HAS_BIAS>
__global__ __launch_bounds__(256) void gemm_bt_kernel(const unsigned short* __restrict__ A,
                                                      const unsigned short* __restrict__ Bt,
                                                      const float* __restrict__ bias,
                                                      unsigned short* __restrict__ C,
                                                      int M, int N, int K) {
    __shared__ __align__(16) unsigned short ldsA[2][4096];
    __shared__ __align__(16) unsigned short ldsB[2][4096];
    int m0 = blockIdx.y * 128;
    int n0 = blockIdx.x * 128;
    int tid = threadIdx.x;
    int wv = tid >> 6, l = tid & 63;
    int wr = wv >> 1, wc = wv & 1;
    int lr = l & 15, lg = l >> 4;
    f32x4 acc[4][4] = {};

    auto stage = [&](int buf, int kt) {
        int k0 = kt * 32;
#pragma unroll
        for (int i = 0; i < 2; i++) {
            int tsk = tid + 256 * i;
            int r = tsk >> 2, g = tsk & 3;
            int gs = (g ^ (r & 3)) * 8;
            __builtin_amdgcn_global_load_lds(
                (const __attribute__((address_space(1))) void*)(A + (size_t)(m0 + r) * K + k0 + gs),
                (__attribute__((address_space(3))) void*)&ldsA[buf][tsk * 8], 16, 0, 0);
        }
#pragma unroll
        for (int i = 0; i < 2; i++) {
            int tsk = tid + 256 * i;
            int r = tsk >> 2, g = tsk & 3;
            int gs = (g ^ (r & 3)) * 8;
            __builtin_amdgcn_global_load_lds(
                (const __attribute__((address_space(1))) void*)(Bt + (size_t)(n0 + r) * K + k0 + gs),
                (__attribute__((address_space(3))) void*)&ldsB[buf][tsk * 8], 16, 0, 0);
        }
    };

    int nt = K >> 5;
    stage(0, 0);
    for (int t = 0; t < nt; t++) {
        int cur = t & 1;
        if (t + 1 < nt) {
            stage(cur ^ 1, t + 1);
            asm volatile("s_waitcnt vmcnt(4)" ::: "memory");
        } else {
            asm volatile("s_waitcnt vmcnt(0)" ::: "memory");
        }
        __builtin_amdgcn_s_barrier();
        bf16x8 af[4], bfr[4];
#pragma unroll
        for (int mi = 0; mi < 4; mi++) {
            int r = wr * 64 + mi * 16 + lr;
            af[mi] = *(const bf16x8*)&ldsA[cur][r * 32 + ((lg ^ (r & 3)) << 3)];
        }
#pragma unroll
        for (int ni = 0; ni < 4; ni++) {
            int c = wc * 64 + ni * 16 + lr;
            bfr[ni] = *(const bf16x8*)&ldsB[cur][c * 32 + ((lg ^ (c & 3)) << 3)];
        }
#pragma unroll
        for (int mi = 0; mi < 4; mi++)
#pragma unroll
            for (int ni = 0; ni < 4; ni++)
                acc[mi][ni] = __builtin_amdgcn_mfma_f32_16x16x32_bf16(af[mi], bfr[ni], acc[mi][ni], 0, 0, 0);
        __builtin_amdgcn_s_barrier();
    }
#pragma unroll
    for (int ni = 0; ni < 4; ni++) {
        int col = n0 + wc * 64 + ni * 16 + lr;
        float bv = HAS_BIAS ? bias[col] : 0.0f;
#pragma unroll
        for (int mi = 0; mi < 4; mi++) {
            int row = m0 + wr * 64 + mi * 16 + lg * 4;
#pragma unroll
            for (int r = 0; r < 4; r++) {
                C[(size_t)(row + r) * N + col] = f2bf(acc[mi][ni][r] + bv);
            }
        }
    }
}

// ---------------- batch-64 MFMA GEMM with K-split: part[ks][64][N] = A[64][Kslab] * W[N][Kslab]^T ----------------
// grid = (N/64, KSPLIT). Tile 64x64, 4 waves (one 16-col n-tile each), dbuf LDS via global_load_lds.
__global__ __launch_bounds__(256) void gemm64_kernel(const unsigned short* __restrict__ A,
                                                     const unsigned short* __restrict__ W,
                                                     float* __restrict__ part,
                                                     int N, int K) {
    __shared__ __align__(16) unsigned short ldsA[2][2048];
    __shared__ __align__(16) unsigned short ldsB[2][2048];
    int n0 = blockIdx.x * 64;
    int slab = K / gridDim.y;
    int kbase = blockIdx.y * slab;
    int tid = threadIdx.x;
    int wv = tid >> 6, l = tid & 63;
    int lr = l & 15, lg = l >> 4;
    int r = tid >> 2, g = tid & 3;
    int gs = (g ^ (r & 3)) * 8;
    int dst = tid * 8;
    f32x4 acc[4] = {};

    auto stage = [&](int buf, int kt) {
        int k0 = kbase + kt * 32;
        __builtin_amdgcn_global_load_lds(
            (const __attribute__((address_space(1))) void*)(A + (size_t)r * K + k0 + gs),
            (__attribute__((address_space(3))) void*)&ldsA[buf][dst], 16, 0, 0);
        __builtin_amdgcn_global_load_lds(
            (const __attribute__((address_space(1))) void*)(W + (size_t)(n0 + r) * K + k0 + gs),
            (__attribute__((address_space(3))) void*)&ldsB[buf][dst], 16, 0, 0);
    };

    int nt = slab >> 5;
    stage(0, 0);
    for (int t = 0; t < nt; t++) {
        int cur = t & 1;
        if (t + 1 < nt) {
            stage(cur ^ 1, t + 1);
            asm volatile("s_waitcnt vmcnt(2)" ::: "memory");
        } else {
            asm volatile("s_waitcnt vmcnt(0)" ::: "memory");
        }
        __builtin_amdgcn_s_barrier();
        bf16x8 af[4];
#pragma unroll
        for (int mi = 0; mi < 4; mi++) {
            int rr = mi * 16 + lr;
            af[mi] = *(const bf16x8*)&ldsA[cur][rr * 32 + ((lg ^ (rr & 3)) << 3)];
        }
        int cc = wv * 16 + lr;
        bf16x8 bf = *(const bf16x8*)&ldsB[cur][cc * 32 + ((lg ^ (cc & 3)) << 3)];
#pragma unroll
        for (int mi = 0; mi < 4; mi++)
            acc[mi] = __builtin_amdgcn_mfma_f32_16x16x32_bf16(af[mi], bf, acc[mi], 0, 0, 0);
        __builtin_amdgcn_s_barrier();
    }
    int col = n0 + wv * 16 + lr;
#pragma unroll
    for (int mi = 0; mi < 4; mi++) {
        int row = mi * 16 + lg * 4;
#pragma unroll
        for (int q = 0; q < 4; q++) {
            part[((size_t)blockIdx.y * 64 + row + q) * N + col] = acc[mi][q];
        }
    }
}

// ---------------- wave reduce helpers ----------------
__device__ __forceinline__ float wave_max64(float v) {
#pragma unroll
    for (int off = 32; off >= 1; off >>= 1) v = fmaxf(v, __shfl_xor(v, off, 64));
    return v;
}
__device__ __forceinline__ float wave_sum64(float v) {
#pragma unroll
    for (int off = 32; off >= 1; off >>= 1) v += __shfl_xor(v, off, 64);
    return v;
}

// ---------------- attention for one (b,h); qh from partials; writes bf16 o ----------------
__global__ __launch_bounds__(256) void attn_kernel(const unsigned short* __restrict__ kvbuf,
                                                   const float* __restrict__ part_qh,
                                                   const float* __restrict__ b_comb,
                                                   unsigned short* __restrict__ o_bf) {
    int bh = blockIdx.x;
    int b = bh >> 3, h = bh & 7;
    __shared__ float sc[N_];
    __shared__ float qv[DH_];
    __shared__ float red[8];
    __shared__ float opart[4][DH_];
    int tid = threadIdx.x;
    int w = tid >> 6, lane = tid & 63;
    if (tid < DH_) {
        float s = b_comb[h * DH_ + tid];
#pragma unroll
        for (int s8 = 0; s8 < 8; s8++) s += part_qh[(size_t)(s8 * 64 + b) * E_ + h * DH_ + tid];
        qv[tid] = s;
    }
    __syncthreads();
    const unsigned short* kb = kvbuf + (size_t)b * N_ * 1024 + h * DH_;
    float myv[4];
#pragma unroll
    for (int i = 0; i < 4; i++) {
        int n = tid + i * 256;
        const unsigned short* kr = kb + (size_t)n * 1024;
        float s = 0.f;
#pragma unroll
        for (int d = 0; d < DH_; d += 8) {
            uint4 pk = *(const uint4*)(kr + d);
            s += bf2f(pk.x) * qv[d + 0] + bf2f(pk.x >> 16) * qv[d + 1]
               + bf2f(pk.y) * qv[d + 2] + bf2f(pk.y >> 16) * qv[d + 3]
               + bf2f(pk.z) * qv[d + 4] + bf2f(pk.z >> 16) * qv[d + 5]
               + bf2f(pk.w) * qv[d + 6] + bf2f(pk.w >> 16) * qv[d + 7];
        }
        myv[i] = s * 0.125f;
    }
    float m = fmaxf(fmaxf(myv[0], myv[1]), fmaxf(myv[2], myv[3]));
    m = wave_max64(m);
    if (lane == 0) red[w] = m;
    __syncthreads();
    m = fmaxf(fmaxf(red[0], red[1]), fmaxf(red[2], red[3]));
    float s = 0.f;
#pragma unroll
    for (int i = 0; i < 4; i++) {
        float e = expf(myv[i] - m);
        sc[tid + i * 256] = e;
        s += e;
    }
    s = wave_sum64(s);
    if (lane == 0) red[4 + w] = s;
    __syncthreads();
    float inv = 1.0f / (red[4] + red[5] + red[6] + red[7]);
    const unsigned short* vb = kvbuf + (size_t)b * N_ * 1024 + E_ + h * DH_;
    float a0 = 0.f, a1 = 0.f;
    int n0 = w * 256;
    for (int i = 0; i < 256; i += 2) {
        a0 += sc[n0 + i]     * bf2f(vb[(size_t)(n0 + i)     * 1024 + lane]);
        a1 += sc[n0 + i + 1] * bf2f(vb[(size_t)(n0 + i + 1) * 1024 + lane]);
    }
    opart[w][lane] = a0 + a1;
    __syncthreads();
    if (tid < DH_) {
        float r = (opart[0][tid] + opart[1][tid] + opart[2][tid] + opart[3][tid]) * inv;
        o_bf[(size_t)b * E_ + h * DH_ + tid] = f2bf(r);
    }
}

// ---------------- reduce oproj partials + LN(o) + LN(z) -> u_bf, fused_bf[o part], zn32 ----------------
__global__ __launch_bounds__(256) void reduce_oln_kernel(const float* __restrict__ part,
                                                         const float* __restrict__ bout,
                                                         const float* __restrict__ og,
                                                         const float* __restrict__ obv,
                                                         const float* __restrict__ z,
                                                         const float* __restrict__ zg,
                                                         const float* __restrict__ zbv,
                                                         unsigned short* __restrict__ u_bf,
                                                         unsigned short* __restrict__ fused_bf,
                                                         float* __restrict__ zn32) {
    int b = blockIdx.x, tid = threadIdx.x;
    __shared__ float red[16];
    float v[2];
#pragma unroll
    for (int i = 0; i < 2; i++) {
        int e = tid + i * 256;
        float s = bout[e];
#pragma unroll
        for (int s8 = 0; s8 < 8; s8++) s += part[(size_t)(s8 * 64 + b) * E_ + e];
        v[i] = s;
    }
    int w = tid >> 6, lane = tid & 63;
    float s1 = v[0] + v[1];
    float s2 = v[0] * v[0] + v[1] * v[1];
#pragma unroll
    for (int off = 32; off >= 1; off >>= 1) { s1 += __shfl_xor(s1, off, 64); s2 += __shfl_xor(s2, off, 64); }
    if (lane == 0) { red[w] = s1; red[4 + w] = s2; }
    __syncthreads();
    s1 = red[0] + red[1] + red[2] + red[3];
    s2 = red[4] + red[5] + red[6] + red[7];
    float mean = s1 * (1.0f / 512.0f);
    float var = s2 * (1.0f / 512.0f) - mean * mean;
    float rstd = 1.0f / sqrtf(var + 1e-5f);
#pragma unroll
    for (int i = 0; i < 2; i++) {
        int e = tid + i * 256;
        unsigned short val = f2bf((v[i] - mean) * rstd * og[e] + obv[e]);
        u_bf[(size_t)b * 1536 + D_ + e] = val;
        fused_bf[(size_t)b * 1536 + D_ + e] = val;
    }
    // LN(z)
    float zl[4];
    float t1 = 0.f, t2 = 0.f;
#pragma unroll
    for (int i = 0; i < 4; i++) {
        int d = tid + i * 256;
        zl[i] = z[(size_t)b * D_ + d];
        t1 += zl[i]; t2 += zl[i] * zl[i];
    }
#pragma unroll
    for (int off = 32; off >= 1; off >>= 1) { t1 += __shfl_xor(t1, off, 64); t2 += __shfl_xor(t2, off, 64); }
    __syncthreads();
    if (lane == 0) { red[8 + w] = t1; red[12 + w] = t2; }
    __syncthreads();
    t1 = red[8] + red[9] + red[10] + red[11];
    t2 = red[12] + red[13] + red[14] + red[15];
    float zmean = t1 * (1.0f / 1024.0f);
    float zvar = t2 * (1.0f / 1024.0f) - zmean * zmean;
    float zr = 1.0f / sqrtf(zvar + 1e-5f);
#pragma unroll
    for (int i = 0; i < 4; i++) {
        int d = tid + i * 256;
        float zn = (zl[i] - zmean) * zr * zg[d] + zbv[d];
        u_bf[(size_t)b * 1536 + d] = f2bf(zn);
        zn32[(size_t)b * D_ + d] = zn;
    }
}

// ---------------- reduce gate/cand partials -> z_bar -> fused_bf[0:1024] ----------------
__global__ __launch_bounds__(256) void reduce_gc_kernel(const float* __restrict__ part,
                                                        const float* __restrict__ gate_b,
                                                        const float* __restrict__ cand_b,
                                                        const float* __restrict__ zn32,
                                                        unsigned short* __restrict__ fused_bf) {
    int b = blockIdx.x, tid = threadIdx.x;
#pragma unroll
    for (int i = 0; i < 4; i++) {
        int j = tid + i * 256;
        float gp = gate_b[j], cp = cand_b[j];
#pragma unroll
        for (int s = 0; s < 8; s++) {
            gp += part[(size_t)(s * 64 + b) * 2048 + j];
            cp += part[(size_t)(s * 64 + b) * 2048 + 1024 + j];
        }
        float gv = 1.0f / (1.0f + expf(-gp));
        float hv = tanhf(cp);
        float zb = (1.0f - gv) * zn32[(size_t)b * D_ + j] + gv * hv;
        fused_bf[(size_t)b * 1536 + j] = f2bf(zb);
    }
}

// ---------------- reduce syn1 partials + gelu -> tbuf_bf ----------------
__global__ __launch_bounds__(256) void reduce_syn1_kernel(const float* __restrict__ part,
                                                          const float* __restrict__ bias,
                                                          unsigned short* __restrict__ tbuf_bf) {
    int b = blockIdx.x, tid = threadIdx.x;
#pragma unroll
    for (int i = 0; i < 8; i++) {
        int j = tid + i * 256;
        float pre = bias[j];
#pragma unroll
        for (int s = 0; s < 8; s++) pre += part[(size_t)(s * 64 + b) * 2048 + j];
        float val = 0.5f * pre * (1.0f + erff(pre * 0.70710678118654752f));
        tbuf_bf[(size_t)b * 2048 + j] = f2bf(val);
    }
}

// ---------------- reduce syn2 partials -> Abuf (f32) ----------------
__global__ __launch_bounds__(256) void reduce_syn2_kernel(const float* __restrict__ part,
                                                          const float* __restrict__ bias,
                                                          float* __restrict__ Aout) {
    int b = blockIdx.x, tid = threadIdx.x;
#pragma unroll
    for (int i = 0; i < 4; i++) {
        int j = tid + i * 256;
        float pre = bias[j];
#pragma unroll
        for (int s = 0; s < 16; s++) pre += part[(size_t)(s * 64 + b) * 1024 + j];
        Aout[(size_t)b * D_ + j] = pre;
    }
}

// ---------------- NLM (per-neuron 2-layer GLU MLP over A history) ----------------
template <int NT>
__global__ __launch_bounds__(256) void nlm_kernel(const float* __restrict__ Abuf,
                                                  const float* __restrict__ w1g,
                                                  const float* __restrict__ b1g,
                                                  const float* __restrict__ w2g,
                                                  const float* __restrict__ b2g,
                                                  float* __restrict__ z,
                                                  float* __restrict__ zt) {
    __shared__ float w1s[4][2048];
    __shared__ float b1s[4][128];
    __shared__ float w2s[4][128];
    __shared__ float b2s[4][2];
    int tid = threadIdx.x;
    int w = tid >> 6, lane = tid & 63;
    int d = blockIdx.x * 4 + w;
    for (int i = lane; i < 2048; i += 64) w1s[w][i] = w1g[(size_t)d * 2048 + i];
    for (int i = lane; i < 128; i += 64) {
        b1s[w][i] = b1g[(size_t)d * 128 + i];
        w2s[w][i] = w2g[(size_t)d * 128 + i];
    }
    if (lane < 2) b2s[w][lane] = b2g[d * 2 + lane];
    __syncthreads();
    const int b = lane;
    float av[NT];
#pragma unroll
    for (int s = 0; s < NT; s++) av[s] = Abuf[(size_t)s * (B_ * D_) + (size_t)b * D_ + d];
    constexpr int moff = M_ - NT;
    float o0 = b2s[w][0], o1 = b2s[w][1];
    for (int hh = 0; hh < 64; hh++) {
        float a = b1s[w][hh], bb = b1s[w][hh + 64];
#pragma unroll
        for (int s = 0; s < NT; s++) {
            float x = av[s];
            a += x * w1s[w][(s + moff) * 128 + hh];
            bb += x * w1s[w][(s + moff) * 128 + hh + 64];
        }
        float z1 = a / (1.0f + expf(-bb));
        o0 += z1 * w2s[w][hh * 2];
        o1 += z1 * w2s[w][hh * 2 + 1];
    }
    float zv = o0 / (1.0f + expf(-o1));
    z[(size_t)b * D_ + d] = zv;
    zt[((size_t)b * T_ + (NT - 1)) * D_ + d] = zv;
}

// ---------------- pair-sync update + head + certainty ----------------
__global__ __launch_bounds__(256) void synchead_kernel(const float* __restrict__ z,
                                                       const int* __restrict__ act_l, const int* __restrict__ act_r,
                                                       const int* __restrict__ out_l, const int* __restrict__ out_r,
                                                       const float* __restrict__ raw_a, const float* __restrict__ raw_o,
                                                       const float* __restrict__ head_w, const float* __restrict__ head_b,
                                                       float* __restrict__ a_a, float* __restrict__ b_a,
                                                       unsigned short* __restrict__ s_a_bf,
                                                       float* __restrict__ a_o, float* __restrict__ b_o,
                                                       float* __restrict__ out_logits, float* __restrict__ out_cert, int t) {
    int b = blockIdx.x, tid = threadIdx.x;
    __shared__ float zv[D_];
    __shared__ float red[4][4];
    for (int i = tid; i < D_; i += 256) zv[i] = z[(size_t)b * D_ + i];
    __syncthreads();
    float l0 = 0.f, l1 = 0.f, l2 = 0.f, l3 = 0.f;
    for (int p = tid; p < P_; p += 256) {
        size_t ip = (size_t)b * P_ + p;
        float zl = zv[act_l[p]], zr = zv[act_r[p]];
        float da = 1.0f / (1.0f + expf(raw_a[p]));
        float aa = da * a_a[ip] + zl * zr;
        float ba = da * b_a[ip] + 1.0f;
        a_a[ip] = aa; b_a[ip] = ba;
        s_a_bf[(size_t)b * P_ + p] = f2bf(aa / sqrtf(ba + 1e-8f));
        float zlo = zv[out_l[p]], zro = zv[out_r[p]];
        float dz = 1.0f / (1.0f + expf(raw_o[p]));
        float ao = dz * a_o[ip] + zlo * zro;
        float bo = dz * b_o[ip] + 1.0f;
        a_o[ip] = ao; b_o[ip] = bo;
        float so = ao / sqrtf(bo + 1e-8f);
        l0 += so * head_w[p];
        l1 += so * head_w[P_ + p];
        l2 += so * head_w[2 * P_ + p];
        l3 += so * head_w[3 * P_ + p];
    }
    int w = tid >> 6, lane = tid & 63;
#pragma unroll
    for (int off = 32; off >= 1; off >>= 1) {
        l0 += __shfl_xor(l0, off, 64);
        l1 += __shfl_xor(l1, off, 64);
        l2 += __shfl_xor(l2, off, 64);
        l3 += __shfl_xor(l3, off, 64);
    }
    if (lane == 0) { red[w][0] = l0; red[w][1] = l1; red[w][2] = l2; red[w][3] = l3; }
    __syncthreads();
    if (tid == 0) {
        float lg[4];
#pragma unroll
        for (int c = 0; c < 4; c++) {
            lg[c] = red[0][c] + red[1][c] + red[2][c] + red[3][c] + head_b[c];
            out_logits[((size_t)b * C_ + c) * T_ + t] = lg[c];
        }
        float m = fmaxf(fmaxf(lg[0], lg[1]), fmaxf(lg[2], lg[3]));
        float e0 = expf(lg[0] - m), e1 = expf(lg[1] - m), e2 = expf(lg[2] - m), e3 = expf(lg[3] - m);
        float inv = 1.0f / (e0 + e1 + e2 + e3);
        float ent = 0.f, pp;
        pp = fmaxf(e0 * inv, 1e-8f); ent -= pp * logf(pp);
        pp = fmaxf(e1 * inv, 1e-8f); ent -= pp * logf(pp);
        pp = fmaxf(e2 * inv, 1e-8f); ent -= pp * logf(pp);
        pp = fmaxf(e3 * inv, 1e-8f); ent -= pp * logf(pp);
        out_cert[(size_t)b * T_ + t] = 1.0f - ent * (1.0f / 1.3862943611198906f);
    }
}

extern "C" void kernel_launch(void* const* d_in, const int* in_sizes, int n_in,
                              void* d_out, int out_size, void* d_ws, size_t ws_size,
                              hipStream_t stream) {
    const float* kv_tokens  = (const float*)d_in[0];
    const float* raw_r_act  = (const float*)d_in[1];
    const float* raw_r_out  = (const float*)d_in[2];
    const float* q_w        = (const float*)d_in[3];
    const float* q_b        = (const float*)d_in[4];
    const float* in_proj_w  = (const float*)d_in[5];
    const float* in_proj_b  = (const float*)d_in[6];
    const float* out_proj_w = (const float*)d_in[7];
    const float* out_proj_b = (const float*)d_in[8];
    const float* z_ln_g     = (const float*)d_in[9];
    const float* z_ln_b     = (const float*)d_in[10];
    const float* o_ln_g     = (const float*)d_in[11];
    const float* o_ln_b     = (const float*)d_in[12];
    const float* gate_w     = (const float*)d_in[13];
    const float* gate_b     = (const float*)d_in[14];
    const float* cand_w     = (const float*)d_in[15];
    const float* cand_b     = (const float*)d_in[16];
    const float* syn1_w     = (const float*)d_in[17];
    const float* syn1_b     = (const float*)d_in[18];
    const float* syn2_w     = (const float*)d_in[19];
    const float* syn2_b     = (const float*)d_in[20];
    const float* nlm1_w     = (const float*)d_in[21];
    const float* nlm1_b     = (const float*)d_in[22];
    const float* nlm2_w     = (const float*)d_in[23];
    const float* nlm2_b     = (const float*)d_in[24];
    const float* head_w     = (const float*)d_in[25];
    const float* head_b     = (const float*)d_in[26];
    const int* act_l        = (const int*)d_in[27];
    const int* act_r        = (const int*)d_in[28];
    const int* out_l        = (const int*)d_in[29];
    const int* out_r        = (const int*)d_in[30];

    float* out = (float*)d_out;
    float* out_logits = out;                       // [B,C,T]
    float* out_cert = out + B_ * C_ * T_;          // [B,T]
    float* out_zt = out_cert + B_ * T_;            // [B,T,D]

    char* ws = (char*)d_ws;
    size_t off = 0;
    auto alloc = [&](size_t bytes) { void* p = ws + off; off += (bytes + 255) & ~(size_t)255; return p; };
    unsigned short* kvbuf   = (unsigned short*)alloc((size_t)B_ * N_ * 1024 * 2);   // 128MB
    // part aliases the kvproj chunk buffer (prep phase only vs tick phase only)
    float* part = (float*)alloc((size_t)4 * 1024 * 1024 + (size_t)512 * 1024);
    unsigned short* kvch_bf = (unsigned short*)part;                                 // 4MB chunk (prep)
    unsigned short* Wkv_bf  = (unsigned short*)alloc((size_t)1024 * E_ * 2);
    unsigned short* Wq_bf   = (unsigned short*)alloc((size_t)E_ * E_ * 2);
    unsigned short* qwT_bf  = (unsigned short*)alloc((size_t)P_ * E_ * 2);
    unsigned short* Wc_bf   = (unsigned short*)alloc((size_t)E_ * P_ * 2);
    unsigned short* Wgc_bf  = (unsigned short*)alloc((size_t)2048 * 1536 * 2);
    unsigned short* Ws1_bf  = (unsigned short*)alloc((size_t)2048 * 1536 * 2);
    unsigned short* Ws2_bf  = (unsigned short*)alloc((size_t)1024 * 2048 * 2);
    unsigned short* Wout_bf = (unsigned short*)alloc((size_t)E_ * E_ * 2);
    float* b_comb = (float*)alloc(E_ * 4);
    unsigned short* s_a_bf  = (unsigned short*)alloc((size_t)B_ * P_ * 2);
    unsigned short* o_bf    = (unsigned short*)alloc((size_t)B_ * E_ * 2);
    unsigned short* u_bf    = (unsigned short*)alloc((size_t)B_ * 1536 * 2);
    unsigned short* fused_bf= (unsigned short*)alloc((size_t)B_ * 1536 * 2);
    unsigned short* tbuf_bf = (unsigned short*)alloc((size_t)B_ * HS_ * 2);
    float* zn32 = (float*)alloc((size_t)B_ * D_ * 4);
    float* a_a  = (float*)alloc((size_t)B_ * P_ * 4);
    float* b_a  = (float*)alloc((size_t)B_ * P_ * 4);
    float* a_o  = (float*)alloc((size_t)B_ * P_ * 4);
    float* b_o  = (float*)alloc((size_t)B_ * P_ * 4);
    float* zbuf = (float*)alloc((size_t)B_ * D_ * 4);
    float* Abuf = (float*)alloc((size_t)T_ * B_ * D_ * 4);

    init_kernel<<<512, 256, 0, stream>>>(s_a_bf, a_a, b_a, a_o, b_o, zbuf);

    // --- one-time weight prep ---
    cvt_bf16_kernel<<<(1024 * E_ / 4 + 255) / 256, 256, 0, stream>>>(in_proj_w + (size_t)E_ * E_, Wkv_bf, 1024 * E_ / 4);
    cvt_bf16_kernel<<<(E_ * E_ / 4 + 255) / 256, 256, 0, stream>>>(in_proj_w, Wq_bf, E_ * E_ / 4);
    cvt_bf16_kernel<<<(1024 * 1536 / 4 + 255) / 256, 256, 0, stream>>>(gate_w, Wgc_bf, 1024 * 1536 / 4);
    cvt_bf16_kernel<<<(1024 * 1536 / 4 + 255) / 256, 256, 0, stream>>>(cand_w, Wgc_bf + (size_t)1024 * 1536, 1024 * 1536 / 4);
    cvt_bf16_kernel<<<(2048 * 1536 / 4 + 255) / 256, 256, 0, stream>>>(syn1_w, Ws1_bf, 2048 * 1536 / 4);
    cvt_bf16_kernel<<<(1024 * 2048 / 4 + 255) / 256, 256, 0, stream>>>(syn2_w, Ws2_bf, 1024 * 2048 / 4);
    cvt_bf16_kernel<<<(E_ * E_ / 4 + 255) / 256, 256, 0, stream>>>(out_proj_w, Wout_bf, E_ * E_ / 4);
    transpose_cvt_kernel<<<dim3(P_ / 32, E_ / 32), 256, 0, stream>>>(q_w, qwT_bf, E_, P_);
    bcomb_kernel<<<2, 256, 0, stream>>>(in_proj_w, in_proj_b, q_b, b_comb);
    gemm_bt_kernel<false><<<dim3(P_ / 128, E_ / 128), 256, 0, stream>>>(Wq_bf, qwT_bf, nullptr, Wc_bf, E_, P_, E_);

    // --- KV projection (chunked cvt + MFMA GEMM) ---
    for (int ch = 0; ch < 16; ch++) {
        const float* src = kv_tokens + (size_t)ch * 4096 * E_;
        cvt_bf16_kernel<<<(4096 * E_ / 4) / 256, 256, 0, stream>>>(src, kvch_bf, 4096 * E_ / 4);
        gemm_bt_kernel<true><<<dim3(8, 32), 256, 0, stream>>>(kvch_bf, Wkv_bf, in_proj_b + E_,
                                                              kvbuf + (size_t)ch * 4096 * 1024, 4096, 1024, E_);
    }

    for (int t = 0; t < T_; t++) {
        // qh partials: [8][64][512]
        gemm64_kernel<<<dim3(8, 8), 256, 0, stream>>>(s_a_bf, Wc_bf, part, E_, P_);
        attn_kernel<<<B_ * NH_, 256, 0, stream>>>(kvbuf, part, b_comb, o_bf);
        // oproj partials: [8][64][512]
        gemm64_kernel<<<dim3(8, 8), 256, 0, stream>>>(o_bf, Wout_bf, part, E_, E_);
        reduce_oln_kernel<<<64, 256, 0, stream>>>(part, out_proj_b, o_ln_g, o_ln_b,
                                                  zbuf, z_ln_g, z_ln_b, u_bf, fused_bf, zn32);
        // gate|cand partials: [8][64][2048]
        gemm64_kernel<<<dim3(32, 8), 256, 0, stream>>>(u_bf, Wgc_bf, part, 2048, 1536);
        reduce_gc_kernel<<<64, 256, 0, stream>>>(part, gate_b, cand_b, zn32, fused_bf);
        // syn1 partials: [8][64][2048]
        gemm64_kernel<<<dim3(32, 8), 256, 0, stream>>>(fused_bf, Ws1_bf, part, 2048, 1536);
        reduce_syn1_kernel<<<64, 256, 0, stream>>>(part, syn1_b, tbuf_bf);
        // syn2 partials: [16][64][1024]
        gemm64_kernel<<<dim3(16, 16), 256, 0, stream>>>(tbuf_bf, Ws2_bf, part, 1024, 2048);
        reduce_syn2_kernel<<<64, 256, 0, stream>>>(part, syn2_b, Abuf + (size_t)t * B_ * D_);
        switch (t) {
            case 0:  nlm_kernel<1><<<256, 256, 0, stream>>>(Abuf, nlm1_w, nlm1_b, nlm2_w, nlm2_b, zbuf, out_zt); break;
            case 1:  nlm_kernel<2><<<256, 256, 0, stream>>>(Abuf, nlm1_w, nlm1_b, nlm2_w, nlm2_b, zbuf, out_zt); break;
            case 2:  nlm_kernel<3><<<256, 256, 0, stream>>>(Abuf, nlm1_w, nlm1_b, nlm2_w, nlm2_b, zbuf, out_zt); break;
            case 3:  nlm_kernel<4><<<256, 256, 0, stream>>>(Abuf, nlm1_w, nlm1_b, nlm2_w, nlm2_b, zbuf, out_zt); break;
            case 4:  nlm_kernel<5><<<256, 256, 0, stream>>>(Abuf, nlm1_w, nlm1_b, nlm2_w, nlm2_b, zbuf, out_zt); break;
            case 5:  nlm_kernel<6><<<256, 256, 0, stream>>>(Abuf, nlm1_w, nlm1_b, nlm2_w, nlm2_b, zbuf, out_zt); break;
            case 6:  nlm_kernel<7><<<256, 256, 0, stream>>>(Abuf, nlm1_w, nlm1_b, nlm2_w, nlm2_b, zbuf, out_zt); break;
            case 7:  nlm_kernel<8><<<256, 256, 0, stream>>>(Abuf, nlm1_w, nlm1_b, nlm2_w, nlm2_b, zbuf, out_zt); break;
            case 8:  nlm_kernel<9><<<256, 256, 0, stream>>>(Abuf, nlm1_w, nlm1_b, nlm2_w, nlm2_b, zbuf, out_zt); break;
            case 9:  nlm_kernel<10><<<256, 256, 0, stream>>>(Abuf, nlm1_w, nlm1_b, nlm2_w, nlm2_b, zbuf, out_zt); break;
            case 10: nlm_kernel<11><<<256, 256, 0, stream>>>(Abuf, nlm1_w, nlm1_b, nlm2_w, nlm2_b, zbuf, out_zt); break;
            default: nlm_kernel<12><<<256, 256, 0, stream>>>(Abuf, nlm1_w, nlm1_b, nlm2_w, nlm2_b, zbuf, out_zt); break;
        }
        synchead_kernel<<<64, 256, 0, stream>>>(zbuf, act_l, act_r, out_l, out_r, raw_r_act, raw_r_out,
                                                head_w, head_b, a_a, b_a, s_a_bf, a_o, b_o,
                                                out_logits, out_cert, t);
    }
}

// Round 4
// 1437.864 us; speedup vs baseline: 4.1715x; 1.3325x over previous
//
#include <hip/hip_runtime.h>
#include <hip/hip_bf16.h>

#define B_ 64
#define N_ 1024
#define E_ 512
#define D_ 1024
#define M_ 16
#define T_ 12
#define P_ 2048
#define HS_ 2048
#define HN_ 64
#define C_ 4
#define NH_ 8
#define DH_ 64

typedef __attribute__((ext_vector_type(8))) short bf16x8;
typedef __attribute__((ext_vector_type(4))) float f32x4;

__device__ __forceinline__ float bf2f(unsigned int u) {
    union { unsigned int i; float f; } c; c.i = (u & 0xffffu) << 16; return c.f;
}
__device__ __forceinline__ unsigned short f2bf(float f) {
    union { float f; unsigned int i; } c; c.f = f;
    unsigned int x = c.i;
    unsigned int r = x + 0x7fffu + ((x >> 16) & 1u);
    return (unsigned short)(r >> 16);
}

// ---------------- init state ----------------
__global__ void init_kernel(unsigned short* s_a_bf, float* a_a, float* b_a, float* a_o, float* b_o, float* z) {
    int i = blockIdx.x * 256 + threadIdx.x;
    if (i < B_ * P_) { a_a[i] = 0.f; b_a[i] = 1.f; a_o[i] = 0.f; b_o[i] = 1.f; s_a_bf[i] = 0; }
    if (i < B_ * D_) z[i] = 0.f;
}

// ---------------- f32 -> bf16 conversion ----------------
__global__ __launch_bounds__(256) void cvt_bf16_kernel(const float* __restrict__ in,
                                                       unsigned short* __restrict__ out, int n4) {
    int i = blockIdx.x * 256 + threadIdx.x;
    if (i < n4) {
        float4 v = ((const float4*)in)[i];
        ushort4 o;
        o.x = f2bf(v.x); o.y = f2bf(v.y); o.z = f2bf(v.z); o.w = f2bf(v.w);
        ((ushort4*)out)[i] = o;
    }
}

// ---------------- interleave gate/cand rows: out row 2j=gate j, 2j+1=cand j ----------------
__global__ __launch_bounds__(256) void cvt_ilv_kernel(const float* __restrict__ g,
                                                      const float* __restrict__ c,
                                                      unsigned short* __restrict__ out) {
    int r = blockIdx.x;  // 0..2047
    const float* src = (r & 1) ? (c + (size_t)(r >> 1) * 1536) : (g + (size_t)(r >> 1) * 1536);
    for (int k = threadIdx.x * 4; k < 1536; k += 1024) {
        float4 v = *(const float4*)(src + k);
        ushort4 o;
        o.x = f2bf(v.x); o.y = f2bf(v.y); o.z = f2bf(v.z); o.w = f2bf(v.w);
        *(ushort4*)(out + (size_t)r * 1536 + k) = o;
    }
}

// ---------------- transpose + cvt: out[c][r] = bf16(in[r][c]) ----------------
__global__ __launch_bounds__(256) void transpose_cvt_kernel(const float* __restrict__ in,
                                                            unsigned short* __restrict__ out,
                                                            int R, int Ccols) {
    __shared__ float tb[32][33];
    int c0 = blockIdx.x * 32, r0 = blockIdx.y * 32;
    int tx = threadIdx.x & 31, ty = threadIdx.x >> 5;
#pragma unroll
    for (int i = 0; i < 32; i += 8) tb[ty + i][tx] = in[(size_t)(r0 + ty + i) * Ccols + c0 + tx];
    __syncthreads();
#pragma unroll
    for (int i = 0; i < 32; i += 8) out[(size_t)(c0 + ty + i) * R + r0 + tx] = f2bf(tb[tx][ty + i]);
}

// ---------------- combined query bias ----------------
__global__ __launch_bounds__(256) void bcomb_kernel(const float* __restrict__ in_proj_w,
                                                    const float* __restrict__ in_proj_b,
                                                    const float* __restrict__ q_b,
                                                    float* __restrict__ bc) {
    int e = blockIdx.x * 256 + threadIdx.x;
    if (e < E_) {
        const float* wr = in_proj_w + (size_t)e * E_;
        float s = in_proj_b[e];
        for (int k = 0; k < E_; k += 4) {
            float4 w4 = *(const float4*)(wr + k);
            float4 q4 = *(const float4*)(q_b + k);
            s += w4.x * q4.x + w4.y * q4.y + w4.z * q4.z + w4.w * q4.w;
        }
        bc[e] = s;
    }
}

// ---------------- big bf16 MFMA GEMM (128x128 tile) + XCD swizzle ----------------
template <bool HAS_BIAS>
__global__ __launch_bounds__(256) void gemm_bt_kernel(const unsigned short* __restrict__ A,
                                                      const unsigned short* __restrict__ Bt,
                                                      const float* __restrict__ bias,
                                                      unsigned short* __restrict__ C,
                                                      int M, int N, int K) {
    __shared__ __align__(16) unsigned short ldsA[2][4096];
    __shared__ __align__(16) unsigned short ldsB[2][4096];
    // XCD-aware swizzle (grid size multiple of 8 in all uses)
    int id = blockIdx.y * gridDim.x + blockIdx.x;
    int nwg = gridDim.x * gridDim.y;
    int swz = (id & 7) * (nwg >> 3) + (id >> 3);
    int bx = swz % gridDim.x, by = swz / gridDim.x;
    int m0 = by * 128;
    int n0 = bx * 128;
    int tid = threadIdx.x;
    int wv = tid >> 6, l = tid & 63;
    int wr = wv >> 1, wc = wv & 1;
    int lr = l & 15, lg = l >> 4;
    f32x4 acc[4][4] = {};

    auto stage = [&](int buf, int kt) {
        int k0 = kt * 32;
#pragma unroll
        for (int i = 0; i < 2; i++) {
            int tsk = tid + 256 * i;
            int r = tsk >> 2, g = tsk & 3;
            int gs = (g ^ (r & 3)) * 8;
            __builtin_amdgcn_global_load_lds(
                (const __attribute__((address_space(1))) void*)(A + (size_t)(m0 + r) * K + k0 + gs),
                (__attribute__((address_space(3))) void*)&ldsA[buf][tsk * 8], 16, 0, 0);
        }
#pragma unroll
        for (int i = 0; i < 2; i++) {
            int tsk = tid + 256 * i;
            int r = tsk >> 2, g = tsk & 3;
            int gs = (g ^ (r & 3)) * 8;
            __builtin_amdgcn_global_load_lds(
                (const __attribute__((address_space(1))) void*)(Bt + (size_t)(n0 + r) * K + k0 + gs),
                (__attribute__((address_space(3))) void*)&ldsB[buf][tsk * 8], 16, 0, 0);
        }
    };

    int nt = K >> 5;
    stage(0, 0);
    for (int t = 0; t < nt; t++) {
        int cur = t & 1;
        if (t + 1 < nt) {
            stage(cur ^ 1, t + 1);
            asm volatile("s_waitcnt vmcnt(4)" ::: "memory");
        } else {
            asm volatile("s_waitcnt vmcnt(0)" ::: "memory");
        }
        __builtin_amdgcn_s_barrier();
        bf16x8 af[4], bfr[4];
#pragma unroll
        for (int mi = 0; mi < 4; mi++) {
            int r = wr * 64 + mi * 16 + lr;
            af[mi] = *(const bf16x8*)&ldsA[cur][r * 32 + ((lg ^ (r & 3)) << 3)];
        }
#pragma unroll
        for (int ni = 0; ni < 4; ni++) {
            int c = wc * 64 + ni * 16 + lr;
            bfr[ni] = *(const bf16x8*)&ldsB[cur][c * 32 + ((lg ^ (c & 3)) << 3)];
        }
#pragma unroll
        for (int mi = 0; mi < 4; mi++)
#pragma unroll
            for (int ni = 0; ni < 4; ni++)
                acc[mi][ni] = __builtin_amdgcn_mfma_f32_16x16x32_bf16(af[mi], bfr[ni], acc[mi][ni], 0, 0, 0);
        __builtin_amdgcn_s_barrier();
    }
#pragma unroll
    for (int ni = 0; ni < 4; ni++) {
        int col = n0 + wc * 64 + ni * 16 + lr;
        float bv = HAS_BIAS ? bias[col] : 0.0f;
#pragma unroll
        for (int mi = 0; mi < 4; mi++) {
            int row = m0 + wr * 64 + mi * 16 + lg * 4;
#pragma unroll
            for (int r = 0; r < 4; r++) {
                C[(size_t)(row + r) * N + col] = f2bf(acc[mi][ni][r] + bv);
            }
        }
    }
}

// ---------------- fused batch-64 GEMM: 64x16 tile, 4 waves K-split, in-block reduce + epilogue ----------------
// EPI 0: bf16 out + bias0 (qh). 1: f32 out, no bias (oproj pre).
// EPI 2: gate/cand interleaved -> z_bar -> fused_bf. 3: gelu -> bf16 (syn1). 4: f32 +bias -> transposed [col][b] (syn2->Abuf_T).
template <int EPI>
__global__ __launch_bounds__(256) void gemmNK_kernel(const unsigned short* __restrict__ A,
                                                     const unsigned short* __restrict__ W,
                                                     const float* __restrict__ bias0,
                                                     const float* __restrict__ bias1,
                                                     const float* __restrict__ zn32,
                                                     void* __restrict__ outp,
                                                     int N, int K) {
    __shared__ __align__(16) unsigned short ldsA[4][2][2048];
    __shared__ __align__(16) unsigned short ldsB[4][2][512];
    int n0 = blockIdx.x * 16;
    int tid = threadIdx.x;
    int w = tid >> 6, l = tid & 63;
    int Kw = K >> 2;
    int kb = w * Kw;
    int lr = l & 15, lg = l >> 4;
    int ar = l >> 2, ag = l & 3;
    f32x4 acc[4] = {};

    auto stage = [&](int buf, int kt) {
        int k0 = kb + (kt << 5);
#pragma unroll
        for (int i = 0; i < 4; i++) {
            int row = i * 16 + ar;
            int gs = (ag ^ (row & 3)) << 3;
            __builtin_amdgcn_global_load_lds(
                (const __attribute__((address_space(1))) void*)(A + (size_t)row * K + k0 + gs),
                (__attribute__((address_space(3))) void*)&ldsA[w][buf][i * 512 + l * 8], 16, 0, 0);
        }
        {
            int col = ar;
            int gs = (ag ^ (col & 3)) << 3;
            __builtin_amdgcn_global_load_lds(
                (const __attribute__((address_space(1))) void*)(W + (size_t)(n0 + col) * K + k0 + gs),
                (__attribute__((address_space(3))) void*)&ldsB[w][buf][l * 8], 16, 0, 0);
        }
    };

    int nt = Kw >> 5;
    stage(0, 0);
    for (int t = 0; t < nt; t++) {
        int cur = t & 1;
        if (t + 1 < nt) {
            stage(cur ^ 1, t + 1);
            asm volatile("s_waitcnt vmcnt(5)" ::: "memory");
        } else {
            asm volatile("s_waitcnt vmcnt(0)" ::: "memory");
        }
        bf16x8 bf = *(const bf16x8*)&ldsB[w][cur][lr * 32 + ((lg ^ (lr & 3)) << 3)];
#pragma unroll
        for (int mi = 0; mi < 4; mi++) {
            int rr = mi * 16 + lr;
            bf16x8 af = *(const bf16x8*)&ldsA[w][cur][rr * 32 + ((lg ^ (rr & 3)) << 3)];
            acc[mi] = __builtin_amdgcn_mfma_f32_16x16x32_bf16(af, bf, acc[mi], 0, 0, 0);
        }
    }
    __syncthreads();
    float* red = (float*)&ldsA[0][0][0];  // [4][64][16] f32 = 16KB
#pragma unroll
    for (int mi = 0; mi < 4; mi++) {
        int row = mi * 16 + lg * 4;
#pragma unroll
        for (int q = 0; q < 4; q++) red[w * 1024 + (row + q) * 16 + lr] = acc[mi][q];
    }
    __syncthreads();
    int b = tid >> 2, c4 = (tid & 3) << 2;
    f32x4 s = *(f32x4*)&red[b * 16 + c4];
#pragma unroll
    for (int ww = 1; ww < 4; ww++) {
        f32x4 v = *(f32x4*)&red[ww * 1024 + b * 16 + c4];
        s[0] += v[0]; s[1] += v[1]; s[2] += v[2]; s[3] += v[3];
    }
    int col = n0 + c4;
    if (EPI == 0) {
        unsigned short* out = (unsigned short*)outp;
        ushort4 o;
        o.x = f2bf(s[0] + bias0[col + 0]);
        o.y = f2bf(s[1] + bias0[col + 1]);
        o.z = f2bf(s[2] + bias0[col + 2]);
        o.w = f2bf(s[3] + bias0[col + 3]);
        *(ushort4*)(out + (size_t)b * N + col) = o;
    } else if (EPI == 1) {
        float* out = (float*)outp;
        *(f32x4*)(out + (size_t)b * N + col) = s;
    } else if (EPI == 2) {
        unsigned short* out = (unsigned short*)outp;  // fused_bf
        int j0 = col >> 1;
#pragma unroll
        for (int pp = 0; pp < 2; pp++) {
            int j = j0 + pp;
            float g = 1.0f / (1.0f + expf(-(s[pp * 2] + bias0[j])));
            float h = tanhf(s[pp * 2 + 1] + bias1[j]);
            float zb = (1.0f - g) * zn32[(size_t)b * D_ + j] + g * h;
            out[(size_t)b * 1536 + j] = f2bf(zb);
        }
    } else if (EPI == 3) {
        unsigned short* out = (unsigned short*)outp;
        ushort4 o;
#pragma unroll
        for (int j = 0; j < 4; j++) {
            float pre = s[j] + bias0[col + j];
            float val = 0.5f * pre * (1.0f + erff(pre * 0.70710678118654752f));
            ((unsigned short*)&o)[j] = f2bf(val);
        }
        *(ushort4*)(out + (size_t)b * N + col) = o;
    } else {  // EPI == 4: transposed f32 out[col][b]
        float* out = (float*)outp;
#pragma unroll
        for (int j = 0; j < 4; j++) {
            out[(size_t)(col + j) * 64 + b] = s[j] + bias0[col + j];
        }
    }
}

// ---------------- wave reduce helpers ----------------
__device__ __forceinline__ float wave_max64(float v) {
#pragma unroll
    for (int off = 32; off >= 1; off >>= 1) v = fmaxf(v, __shfl_xor(v, off, 64));
    return v;
}
__device__ __forceinline__ float wave_sum64(float v) {
#pragma unroll
    for (int off = 32; off >= 1; off >>= 1) v += __shfl_xor(v, off, 64);
    return v;
}

// ---------------- attention for one (b,h) ----------------
__global__ __launch_bounds__(256) void attn_kernel(const unsigned short* __restrict__ kvbuf,
                                                   const unsigned short* __restrict__ qh_bf,
                                                   unsigned short* __restrict__ o_bf) {
    int bh = blockIdx.x;
    int b = bh >> 3, h = bh & 7;
    __shared__ float sc[N_];
    __shared__ float qv[DH_];
    __shared__ float red[8];
    __shared__ float opart[4][DH_];
    int tid = threadIdx.x;
    int w = tid >> 6, lane = tid & 63;
    if (tid < DH_) qv[tid] = bf2f(qh_bf[(size_t)b * E_ + h * DH_ + tid]);
    __syncthreads();
    const unsigned short* kb = kvbuf + (size_t)b * N_ * 1024 + h * DH_;
    float myv[4];
#pragma unroll
    for (int i = 0; i < 4; i++) {
        int n = tid + i * 256;
        const unsigned short* kr = kb + (size_t)n * 1024;
        float s = 0.f;
#pragma unroll
        for (int d = 0; d < DH_; d += 8) {
            uint4 pk = *(const uint4*)(kr + d);
            s += bf2f(pk.x) * qv[d + 0] + bf2f(pk.x >> 16) * qv[d + 1]
               + bf2f(pk.y) * qv[d + 2] + bf2f(pk.y >> 16) * qv[d + 3]
               + bf2f(pk.z) * qv[d + 4] + bf2f(pk.z >> 16) * qv[d + 5]
               + bf2f(pk.w) * qv[d + 6] + bf2f(pk.w >> 16) * qv[d + 7];
        }
        myv[i] = s * 0.125f;
    }
    float m = fmaxf(fmaxf(myv[0], myv[1]), fmaxf(myv[2], myv[3]));
    m = wave_max64(m);
    if (lane == 0) red[w] = m;
    __syncthreads();
    m = fmaxf(fmaxf(red[0], red[1]), fmaxf(red[2], red[3]));
    float s = 0.f;
#pragma unroll
    for (int i = 0; i < 4; i++) {
        float e = expf(myv[i] - m);
        sc[tid + i * 256] = e;
        s += e;
    }
    s = wave_sum64(s);
    if (lane == 0) red[4 + w] = s;
    __syncthreads();
    float inv = 1.0f / (red[4] + red[5] + red[6] + red[7]);
    // V pass: lane covers 4 d's, 4 n's per iteration (uint2 = 8B/lane)
    const unsigned short* vb = kvbuf + (size_t)b * N_ * 1024 + E_ + h * DH_;
    int ng = lane >> 4, d4 = (lane & 15) << 2;
    float a0 = 0.f, a1 = 0.f, a2 = 0.f, a3 = 0.f;
    int n0 = w * 256;
    for (int i = 0; i < 64; i++) {
        int n = n0 + i * 4 + ng;
        uint2 pv = *(const uint2*)(vb + (size_t)n * 1024 + d4);
        float sv = sc[n];
        a0 += sv * bf2f(pv.x);
        a1 += sv * bf2f(pv.x >> 16);
        a2 += sv * bf2f(pv.y);
        a3 += sv * bf2f(pv.y >> 16);
    }
    a0 += __shfl_xor(a0, 16, 64); a0 += __shfl_xor(a0, 32, 64);
    a1 += __shfl_xor(a1, 16, 64); a1 += __shfl_xor(a1, 32, 64);
    a2 += __shfl_xor(a2, 16, 64); a2 += __shfl_xor(a2, 32, 64);
    a3 += __shfl_xor(a3, 16, 64); a3 += __shfl_xor(a3, 32, 64);
    if (lane < 16) {
        opart[w][d4 + 0] = a0;
        opart[w][d4 + 1] = a1;
        opart[w][d4 + 2] = a2;
        opart[w][d4 + 3] = a3;
    }
    __syncthreads();
    if (tid < DH_) {
        float r = (opart[0][tid] + opart[1][tid] + opart[2][tid] + opart[3][tid]) * inv;
        o_bf[(size_t)b * E_ + h * DH_ + tid] = f2bf(r);
    }
}

// ---------------- reduce oproj pre (f32) + LN(o) + LN(z) -> u_bf, fused_bf[o], zn32 ----------------
__global__ __launch_bounds__(256) void reduce_oln_kernel(const float* __restrict__ opre,
                                                         const float* __restrict__ bout,
                                                         const float* __restrict__ og,
                                                         const float* __restrict__ obv,
                                                         const float* __restrict__ z,
                                                         const float* __restrict__ zg,
                                                         const float* __restrict__ zbv,
                                                         unsigned short* __restrict__ u_bf,
                                                         unsigned short* __restrict__ fused_bf,
                                                         float* __restrict__ zn32) {
    int b = blockIdx.x, tid = threadIdx.x;
    __shared__ float red[16];
    float v[2];
#pragma unroll
    for (int i = 0; i < 2; i++) {
        int e = tid + i * 256;
        v[i] = opre[(size_t)b * E_ + e] + bout[e];
    }
    int w = tid >> 6, lane = tid & 63;
    float s1 = v[0] + v[1];
    float s2 = v[0] * v[0] + v[1] * v[1];
#pragma unroll
    for (int off = 32; off >= 1; off >>= 1) { s1 += __shfl_xor(s1, off, 64); s2 += __shfl_xor(s2, off, 64); }
    if (lane == 0) { red[w] = s1; red[4 + w] = s2; }
    __syncthreads();
    s1 = red[0] + red[1] + red[2] + red[3];
    s2 = red[4] + red[5] + red[6] + red[7];
    float mean = s1 * (1.0f / 512.0f);
    float var = s2 * (1.0f / 512.0f) - mean * mean;
    float rstd = 1.0f / sqrtf(var + 1e-5f);
#pragma unroll
    for (int i = 0; i < 2; i++) {
        int e = tid + i * 256;
        unsigned short val = f2bf((v[i] - mean) * rstd * og[e] + obv[e]);
        u_bf[(size_t)b * 1536 + D_ + e] = val;
        fused_bf[(size_t)b * 1536 + D_ + e] = val;
    }
    float zl[4];
    float t1 = 0.f, t2 = 0.f;
#pragma unroll
    for (int i = 0; i < 4; i++) {
        int d = tid + i * 256;
        zl[i] = z[(size_t)b * D_ + d];
        t1 += zl[i]; t2 += zl[i] * zl[i];
    }
#pragma unroll
    for (int off = 32; off >= 1; off >>= 1) { t1 += __shfl_xor(t1, off, 64); t2 += __shfl_xor(t2, off, 64); }
    __syncthreads();
    if (lane == 0) { red[8 + w] = t1; red[12 + w] = t2; }
    __syncthreads();
    t1 = red[8] + red[9] + red[10] + red[11];
    t2 = red[12] + red[13] + red[14] + red[15];
    float zmean = t1 * (1.0f / 1024.0f);
    float zvar = t2 * (1.0f / 1024.0f) - zmean * zmean;
    float zr = 1.0f / sqrtf(zvar + 1e-5f);
#pragma unroll
    for (int i = 0; i < 4; i++) {
        int d = tid + i * 256;
        float zn = (zl[i] - zmean) * zr * zg[d] + zbv[d];
        u_bf[(size_t)b * 1536 + d] = f2bf(zn);
        zn32[(size_t)b * D_ + d] = zn;
    }
}

// ---------------- NLM over transposed history Abuf_T [t][d][b] ----------------
template <int NT>
__global__ __launch_bounds__(256) void nlm_kernel(const float* __restrict__ AbufT,
                                                  const float* __restrict__ w1g,
                                                  const float* __restrict__ b1g,
                                                  const float* __restrict__ w2g,
                                                  const float* __restrict__ b2g,
                                                  float* __restrict__ z,
                                                  float* __restrict__ zt) {
    __shared__ float w1s[4][2048];
    __shared__ float b1s[4][128];
    __shared__ float w2s[4][128];
    __shared__ float b2s[4][2];
    int tid = threadIdx.x;
    int w = tid >> 6, lane = tid & 63;
    int d = blockIdx.x * 4 + w;
    for (int i = lane; i < 2048; i += 64) w1s[w][i] = w1g[(size_t)d * 2048 + i];
    for (int i = lane; i < 128; i += 64) {
        b1s[w][i] = b1g[(size_t)d * 128 + i];
        w2s[w][i] = w2g[(size_t)d * 128 + i];
    }
    if (lane < 2) b2s[w][lane] = b2g[d * 2 + lane];
    __syncthreads();
    const int b = lane;
    float av[NT];
#pragma unroll
    for (int s = 0; s < NT; s++) av[s] = AbufT[((size_t)s * D_ + d) * 64 + b];
    constexpr int moff = M_ - NT;
    float o0 = b2s[w][0], o1 = b2s[w][1];
    for (int hh = 0; hh < 64; hh++) {
        float a = b1s[w][hh], bb = b1s[w][hh + 64];
#pragma unroll
        for (int s = 0; s < NT; s++) {
            float x = av[s];
            a += x * w1s[w][(s + moff) * 128 + hh];
            bb += x * w1s[w][(s + moff) * 128 + hh + 64];
        }
        float z1 = a / (1.0f + expf(-bb));
        o0 += z1 * w2s[w][hh * 2];
        o1 += z1 * w2s[w][hh * 2 + 1];
    }
    float zv = o0 / (1.0f + expf(-o1));
    z[(size_t)b * D_ + d] = zv;
    zt[((size_t)b * T_ + (NT - 1)) * D_ + d] = zv;
}

// ---------------- pair-sync update + head + certainty ----------------
__global__ __launch_bounds__(256) void synchead_kernel(const float* __restrict__ z,
                                                       const int* __restrict__ act_l, const int* __restrict__ act_r,
                                                       const int* __restrict__ out_l, const int* __restrict__ out_r,
                                                       const float* __restrict__ raw_a, const float* __restrict__ raw_o,
                                                       const float* __restrict__ head_w, const float* __restrict__ head_b,
                                                       float* __restrict__ a_a, float* __restrict__ b_a,
                                                       unsigned short* __restrict__ s_a_bf,
                                                       float* __restrict__ a_o, float* __restrict__ b_o,
                                                       float* __restrict__ out_logits, float* __restrict__ out_cert, int t) {
    int b = blockIdx.x, tid = threadIdx.x;
    __shared__ float zv[D_];
    __shared__ float red[4][4];
    for (int i = tid; i < D_; i += 256) zv[i] = z[(size_t)b * D_ + i];
    __syncthreads();
    float l0 = 0.f, l1 = 0.f, l2 = 0.f, l3 = 0.f;
    for (int p = tid; p < P_; p += 256) {
        size_t ip = (size_t)b * P_ + p;
        float zl = zv[act_l[p]], zr = zv[act_r[p]];
        float da = 1.0f / (1.0f + expf(raw_a[p]));
        float aa = da * a_a[ip] + zl * zr;
        float ba = da * b_a[ip] + 1.0f;
        a_a[ip] = aa; b_a[ip] = ba;
        s_a_bf[(size_t)b * P_ + p] = f2bf(aa / sqrtf(ba + 1e-8f));
        float zlo = zv[out_l[p]], zro = zv[out_r[p]];
        float dz = 1.0f / (1.0f + expf(raw_o[p]));
        float ao = dz * a_o[ip] + zlo * zro;
        float bo = dz * b_o[ip] + 1.0f;
        a_o[ip] = ao; b_o[ip] = bo;
        float so = ao / sqrtf(bo + 1e-8f);
        l0 += so * head_w[p];
        l1 += so * head_w[P_ + p];
        l2 += so * head_w[2 * P_ + p];
        l3 += so * head_w[3 * P_ + p];
    }
    int w = tid >> 6, lane = tid & 63;
#pragma unroll
    for (int off = 32; off >= 1; off >>= 1) {
        l0 += __shfl_xor(l0, off, 64);
        l1 += __shfl_xor(l1, off, 64);
        l2 += __shfl_xor(l2, off, 64);
        l3 += __shfl_xor(l3, off, 64);
    }
    if (lane == 0) { red[w][0] = l0; red[w][1] = l1; red[w][2] = l2; red[w][3] = l3; }
    __syncthreads();
    if (tid == 0) {
        float lg[4];
#pragma unroll
        for (int c = 0; c < 4; c++) {
            lg[c] = red[0][c] + red[1][c] + red[2][c] + red[3][c] + head_b[c];
            out_logits[((size_t)b * C_ + c) * T_ + t] = lg[c];
        }
        float m = fmaxf(fmaxf(lg[0], lg[1]), fmaxf(lg[2], lg[3]));
        float e0 = expf(lg[0] - m), e1 = expf(lg[1] - m), e2 = expf(lg[2] - m), e3 = expf(lg[3] - m);
        float inv = 1.0f / (e0 + e1 + e2 + e3);
        float ent = 0.f, pp;
        pp = fmaxf(e0 * inv, 1e-8f); ent -= pp * logf(pp);
        pp = fmaxf(e1 * inv, 1e-8f); ent -= pp * logf(pp);
        pp = fmaxf(e2 * inv, 1e-8f); ent -= pp * logf(pp);
        pp = fmaxf(e3 * inv, 1e-8f); ent -= pp * logf(pp);
        out_cert[(size_t)b * T_ + t] = 1.0f - ent * (1.0f / 1.3862943611198906f);
    }
}

extern "C" void kernel_launch(void* const* d_in, const int* in_sizes, int n_in,
                              void* d_out, int out_size, void* d_ws, size_t ws_size,
                              hipStream_t stream) {
    const float* kv_tokens  = (const float*)d_in[0];
    const float* raw_r_act  = (const float*)d_in[1];
    const float* raw_r_out  = (const float*)d_in[2];
    const float* q_w        = (const float*)d_in[3];
    const float* q_b        = (const float*)d_in[4];
    const float* in_proj_w  = (const float*)d_in[5];
    const float* in_proj_b  = (const float*)d_in[6];
    const float* out_proj_w = (const float*)d_in[7];
    const float* out_proj_b = (const float*)d_in[8];
    const float* z_ln_g     = (const float*)d_in[9];
    const float* z_ln_b     = (const float*)d_in[10];
    const float* o_ln_g     = (const float*)d_in[11];
    const float* o_ln_b     = (const float*)d_in[12];
    const float* gate_w     = (const float*)d_in[13];
    const float* gate_b     = (const float*)d_in[14];
    const float* cand_w     = (const float*)d_in[15];
    const float* cand_b     = (const float*)d_in[16];
    const float* syn1_w     = (const float*)d_in[17];
    const float* syn1_b     = (const float*)d_in[18];
    const float* syn2_w     = (const float*)d_in[19];
    const float* syn2_b     = (const float*)d_in[20];
    const float* nlm1_w     = (const float*)d_in[21];
    const float* nlm1_b     = (const float*)d_in[22];
    const float* nlm2_w     = (const float*)d_in[23];
    const float* nlm2_b     = (const float*)d_in[24];
    const float* head_w     = (const float*)d_in[25];
    const float* head_b     = (const float*)d_in[26];
    const int* act_l        = (const int*)d_in[27];
    const int* act_r        = (const int*)d_in[28];
    const int* out_l        = (const int*)d_in[29];
    const int* out_r        = (const int*)d_in[30];

    float* out = (float*)d_out;
    float* out_logits = out;                       // [B,C,T]
    float* out_cert = out + B_ * C_ * T_;          // [B,T]
    float* out_zt = out_cert + B_ * T_;            // [B,T,D]

    char* ws = (char*)d_ws;
    size_t off = 0;
    auto alloc = [&](size_t bytes) { void* p = ws + off; off += (bytes + 255) & ~(size_t)255; return p; };
    unsigned short* kvbuf   = (unsigned short*)alloc((size_t)B_ * N_ * 1024 * 2);   // 128MB
    unsigned short* kv_bf   = (unsigned short*)alloc((size_t)B_ * N_ * E_ * 2);     // 64MB
    unsigned short* Wkv_bf  = (unsigned short*)alloc((size_t)1024 * E_ * 2);
    unsigned short* Wq_bf   = (unsigned short*)alloc((size_t)E_ * E_ * 2);
    unsigned short* qwT_bf  = (unsigned short*)alloc((size_t)P_ * E_ * 2);
    unsigned short* Wc_bf   = (unsigned short*)alloc((size_t)E_ * P_ * 2);
    unsigned short* Wgc_bf  = (unsigned short*)alloc((size_t)2048 * 1536 * 2);      // interleaved gate/cand
    unsigned short* Ws1_bf  = (unsigned short*)alloc((size_t)2048 * 1536 * 2);
    unsigned short* Ws2_bf  = (unsigned short*)alloc((size_t)1024 * 2048 * 2);
    unsigned short* Wout_bf = (unsigned short*)alloc((size_t)E_ * E_ * 2);
    float* b_comb = (float*)alloc(E_ * 4);
    unsigned short* s_a_bf  = (unsigned short*)alloc((size_t)B_ * P_ * 2);
    unsigned short* qh_bf   = (unsigned short*)alloc((size_t)B_ * E_ * 2);
    unsigned short* o_bf    = (unsigned short*)alloc((size_t)B_ * E_ * 2);
    unsigned short* u_bf    = (unsigned short*)alloc((size_t)B_ * 1536 * 2);
    unsigned short* fused_bf= (unsigned short*)alloc((size_t)B_ * 1536 * 2);
    unsigned short* tbuf_bf = (unsigned short*)alloc((size_t)B_ * HS_ * 2);
    float* opre = (float*)alloc((size_t)B_ * E_ * 4);
    float* zn32 = (float*)alloc((size_t)B_ * D_ * 4);
    float* a_a  = (float*)alloc((size_t)B_ * P_ * 4);
    float* b_a  = (float*)alloc((size_t)B_ * P_ * 4);
    float* a_o  = (float*)alloc((size_t)B_ * P_ * 4);
    float* b_o  = (float*)alloc((size_t)B_ * P_ * 4);
    float* zbuf = (float*)alloc((size_t)B_ * D_ * 4);
    float* AbufT = (float*)alloc((size_t)T_ * D_ * B_ * 4);   // [t][d][b]

    init_kernel<<<512, 256, 0, stream>>>(s_a_bf, a_a, b_a, a_o, b_o, zbuf);

    // --- one-time weight prep ---
    cvt_bf16_kernel<<<(1024 * E_ / 4 + 255) / 256, 256, 0, stream>>>(in_proj_w + (size_t)E_ * E_, Wkv_bf, 1024 * E_ / 4);
    cvt_bf16_kernel<<<(E_ * E_ / 4 + 255) / 256, 256, 0, stream>>>(in_proj_w, Wq_bf, E_ * E_ / 4);
    cvt_ilv_kernel<<<2048, 256, 0, stream>>>(gate_w, cand_w, Wgc_bf);
    cvt_bf16_kernel<<<(2048 * 1536 / 4 + 255) / 256, 256, 0, stream>>>(syn1_w, Ws1_bf, 2048 * 1536 / 4);
    cvt_bf16_kernel<<<(1024 * 2048 / 4 + 255) / 256, 256, 0, stream>>>(syn2_w, Ws2_bf, 1024 * 2048 / 4);
    cvt_bf16_kernel<<<(E_ * E_ / 4 + 255) / 256, 256, 0, stream>>>(out_proj_w, Wout_bf, E_ * E_ / 4);
    transpose_cvt_kernel<<<dim3(P_ / 32, E_ / 32), 256, 0, stream>>>(q_w, qwT_bf, E_, P_);
    bcomb_kernel<<<2, 256, 0, stream>>>(in_proj_w, in_proj_b, q_b, b_comb);
    gemm_bt_kernel<false><<<dim3(P_ / 128, E_ / 128), 256, 0, stream>>>(Wq_bf, qwT_bf, nullptr, Wc_bf, E_, P_, E_);

    // --- KV projection: one cvt + one big MFMA GEMM ---
    cvt_bf16_kernel<<<(B_ * N_ * E_ / 4) / 256, 256, 0, stream>>>(kv_tokens, kv_bf, B_ * N_ * E_ / 4);
    gemm_bt_kernel<true><<<dim3(8, 512), 256, 0, stream>>>(kv_bf, Wkv_bf, in_proj_b + E_,
                                                           kvbuf, B_ * N_, 1024, E_);

    for (int t = 0; t < T_; t++) {
        // qh = s_a @ Wc^T + b_comb -> bf16 [64][512]
        gemmNK_kernel<0><<<32, 256, 0, stream>>>(s_a_bf, Wc_bf, b_comb, nullptr, nullptr, qh_bf, E_, P_);
        attn_kernel<<<B_ * NH_, 256, 0, stream>>>(kvbuf, qh_bf, o_bf);
        // o @ Wout^T -> f32 pre (bias added in LN kernel)
        gemmNK_kernel<1><<<32, 256, 0, stream>>>(o_bf, Wout_bf, nullptr, nullptr, nullptr, opre, E_, E_);
        reduce_oln_kernel<<<64, 256, 0, stream>>>(opre, out_proj_b, o_ln_g, o_ln_b,
                                                  zbuf, z_ln_g, z_ln_b, u_bf, fused_bf, zn32);
        // gate|cand (interleaved) -> z_bar -> fused_bf[:,0:1024]
        gemmNK_kernel<2><<<128, 256, 0, stream>>>(u_bf, Wgc_bf, gate_b, cand_b, zn32, fused_bf, 2048, 1536);
        // syn1 + gelu -> tbuf_bf
        gemmNK_kernel<3><<<128, 256, 0, stream>>>(fused_bf, Ws1_bf, syn1_b, nullptr, nullptr, tbuf_bf, 2048, 1536);
        // syn2 + bias -> AbufT[t] (transposed [d][b])
        gemmNK_kernel<4><<<64, 256, 0, stream>>>(tbuf_bf, Ws2_bf, syn2_b, nullptr, nullptr,
                                                 AbufT + (size_t)t * D_ * 64, 1024, 2048);
        switch (t) {
            case 0:  nlm_kernel<1><<<256, 256, 0, stream>>>(AbufT, nlm1_w, nlm1_b, nlm2_w, nlm2_b, zbuf, out_zt); break;
            case 1:  nlm_kernel<2><<<256, 256, 0, stream>>>(AbufT, nlm1_w, nlm1_b, nlm2_w, nlm2_b, zbuf, out_zt); break;
            case 2:  nlm_kernel<3><<<256, 256, 0, stream>>>(AbufT, nlm1_w, nlm1_b, nlm2_w, nlm2_b, zbuf, out_zt); break;
            case 3:  nlm_kernel<4><<<256, 256, 0, stream>>>(AbufT, nlm1_w, nlm1_b, nlm2_w, nlm2_b, zbuf, out_zt); break;
            case 4:  nlm_kernel<5><<<256, 256, 0, stream>>>(AbufT, nlm1_w, nlm1_b, nlm2_w, nlm2_b, zbuf, out_zt); break;
            case 5:  nlm_kernel<6><<<256, 256, 0, stream>>>(AbufT, nlm1_w, nlm1_b, nlm2_w, nlm2_b, zbuf, out_zt); break;
            case 6:  nlm_kernel<7><<<256, 256, 0, stream>>>(AbufT, nlm1_w, nlm1_b, nlm2_w, nlm2_b, zbuf, out_zt); break;
            case 7:  nlm_kernel<8><<<256, 256, 0, stream>>>(AbufT, nlm1_w, nlm1_b, nlm2_w, nlm2_b, zbuf, out_zt); break;
            case 8:  nlm_kernel<9><<<256, 256, 0, stream>>>(AbufT, nlm1_w, nlm1_b, nlm2_w, nlm2_b, zbuf, out_zt); break;
            case 9:  nlm_kernel<10><<<256, 256, 0, stream>>>(AbufT, nlm1_w, nlm1_b, nlm2_w, nlm2_b, zbuf, out_zt); break;
            case 10: nlm_kernel<11><<<256, 256, 0, stream>>>(AbufT, nlm1_w, nlm1_b, nlm2_w, nlm2_b, zbuf, out_zt); break;
            default: nlm_kernel<12><<<256, 256, 0, stream>>>(AbufT, nlm1_w, nlm1_b, nlm2_w, nlm2_b, zbuf, out_zt); break;
        }
        synchead_kernel<<<64, 256, 0, stream>>>(zbuf, act_l, act_r, out_l, out_r, raw_r_act, raw_r_out,
                                                head_w, head_b, a_a, b_a, s_a_bf, a_o, b_o,
                                                out_logits, out_cert, t);
    }
}